// Round 2
// baseline (4736.783 us; speedup 1.0000x reference)
//
#include <hip/hip_runtime.h>
#include <hip/hip_bf16.h>
#include <math.h>

#define HDIM 512

__device__ __forceinline__ float sigmoidf_(float x) { return 1.0f / (1.0f + __expf(-x)); }

// ---------------- gather: h0[b, j, i*128+e] = emb[ids[b, i*13+j]][e]  (b chunk-local) ----------------
__global__ __launch_bounds__(512) void gather_kernel(const int* __restrict__ ids,
                                                     const float* __restrict__ emb,
                                                     float* __restrict__ H) {
    int bj = blockIdx.x;            // 0..13*C-1  (b*13 + j), chunk-local
    int b = bj / 13, j = bj - b * 13;
    int c = threadIdx.x;            // 0..511
    int i = c >> 7, e = c & 127;
    int id = ids[b * 52 + i * 13 + j];
    H[(size_t)bj * HDIM + c] = emb[(size_t)id * 128 + e];
}

// ---------------- a = At @ h + b_ah (per-graph 13x13 bmm, b chunk-local) ----------------
__global__ __launch_bounds__(512) void a_kernel(const float* __restrict__ Ain,
                                                const float* __restrict__ H,
                                                const float* __restrict__ bah,
                                                float* __restrict__ Aout) {
    int b = blockIdx.x;
    int c = threadIdx.x;            // channel 0..511
    __shared__ float As[169];
    if (c < 169) As[c] = Ain[b * 169 + c];
    float hreg[13];
#pragma unroll
    for (int j = 0; j < 13; ++j) hreg[j] = H[(size_t)(b * 13 + j) * HDIM + c];
    __syncthreads();
    float bb = bah[c];
#pragma unroll
    for (int i = 0; i < 13; ++i) {
        float acc = bb;
#pragma unroll
        for (int j = 0; j < 13; ++j) acc = fmaf(As[j * 13 + i], hreg[j], acc);
        Aout[(size_t)(b * 13 + i) * HDIM + c] = acc;
    }
}

// ---------------- zr_gemm: z = sigmoid(a@wz^T + h@uz^T + b), rh = sigmoid(a@wr^T + h@ur^T + b) * h
// M=13C, N=512, K=512. Tile 64x64, BK=16, 256 threads, 4x4 per thread, 2 acc sets.
__global__ __launch_bounds__(256) void zr_gemm(
    const float* __restrict__ Ab, const float* __restrict__ Hb,
    const float* __restrict__ wz, const float* __restrict__ uz,
    const float* __restrict__ wr, const float* __restrict__ ur,
    const float* __restrict__ bwz, const float* __restrict__ buz,
    const float* __restrict__ bwr, const float* __restrict__ bur,
    float* __restrict__ Zb, float* __restrict__ RHb) {
    __shared__ float xa[16][68], xh[16][68], wls[4][16][68];
    int t = threadIdx.x;
    int m_base = blockIdx.x * 64;
    int n_base = blockIdx.y * 64;
    int lr = t >> 2, lk = (t & 3) * 4;
    int tn = t & 15, tm = t >> 4;
    int m0 = tm * 4, n0 = tn * 4;
    float zacc[4][4] = {}, racc[4][4] = {};
    size_t xoff = (size_t)(m_base + lr) * HDIM + lk;
    size_t woff = (size_t)(n_base + lr) * HDIM + lk;
    for (int kc = 0; kc < 512; kc += 16) {
        float4 va = *(const float4*)&Ab[xoff + kc];
        float4 vh = *(const float4*)&Hb[xoff + kc];
        float4 v0 = *(const float4*)&wz[woff + kc];
        float4 v1 = *(const float4*)&uz[woff + kc];
        float4 v2 = *(const float4*)&wr[woff + kc];
        float4 v3 = *(const float4*)&ur[woff + kc];
        __syncthreads();
        {
            const float* p;
            p = (const float*)&va;
#pragma unroll
            for (int u = 0; u < 4; ++u) xa[lk + u][lr] = p[u];
            p = (const float*)&vh;
#pragma unroll
            for (int u = 0; u < 4; ++u) xh[lk + u][lr] = p[u];
            p = (const float*)&v0;
#pragma unroll
            for (int u = 0; u < 4; ++u) wls[0][lk + u][lr] = p[u];
            p = (const float*)&v1;
#pragma unroll
            for (int u = 0; u < 4; ++u) wls[1][lk + u][lr] = p[u];
            p = (const float*)&v2;
#pragma unroll
            for (int u = 0; u < 4; ++u) wls[2][lk + u][lr] = p[u];
            p = (const float*)&v3;
#pragma unroll
            for (int u = 0; u < 4; ++u) wls[3][lk + u][lr] = p[u];
        }
        __syncthreads();
#pragma unroll
        for (int kk = 0; kk < 16; ++kk) {
            float4 a4 = *(float4*)&xa[kk][m0];
            float4 h4 = *(float4*)&xh[kk][m0];
            float4 wz4 = *(float4*)&wls[0][kk][n0];
            float4 uz4 = *(float4*)&wls[1][kk][n0];
            float4 wr4 = *(float4*)&wls[2][kk][n0];
            float4 ur4 = *(float4*)&wls[3][kk][n0];
            float aa[4] = {a4.x, a4.y, a4.z, a4.w};
            float hh[4] = {h4.x, h4.y, h4.z, h4.w};
            float wzv[4] = {wz4.x, wz4.y, wz4.z, wz4.w};
            float uzv[4] = {uz4.x, uz4.y, uz4.z, uz4.w};
            float wrv[4] = {wr4.x, wr4.y, wr4.z, wr4.w};
            float urv[4] = {ur4.x, ur4.y, ur4.z, ur4.w};
#pragma unroll
            for (int i = 0; i < 4; ++i)
#pragma unroll
                for (int j = 0; j < 4; ++j) {
                    zacc[i][j] = fmaf(aa[i], wzv[j], fmaf(hh[i], uzv[j], zacc[i][j]));
                    racc[i][j] = fmaf(aa[i], wrv[j], fmaf(hh[i], urv[j], racc[i][j]));
                }
        }
    }
#pragma unroll
    for (int i = 0; i < 4; ++i) {
        int m = m_base + m0 + i;
        int n = n_base + n0;
        float4 hq = *(const float4*)&Hb[(size_t)m * HDIM + n];
        float hh[4] = {hq.x, hq.y, hq.z, hq.w};
        float zo[4], ro[4];
#pragma unroll
        for (int j = 0; j < 4; ++j) {
            float zp = zacc[i][j] + bwz[n + j] + buz[n + j];
            float rp = racc[i][j] + bwr[n + j] + bur[n + j];
            zo[j] = sigmoidf_(zp);
            ro[j] = sigmoidf_(rp) * hh[j];
        }
        *(float4*)&Zb[(size_t)m * HDIM + n] = make_float4(zo[0], zo[1], zo[2], zo[3]);
        *(float4*)&RHb[(size_t)m * HDIM + n] = make_float4(ro[0], ro[1], ro[2], ro[3]);
    }
}

// ---------------- c_gemm: c = tanh(a@w^T + rh@u^T + b); hnew = (1-z)h + z*c, written over Zb
__global__ __launch_bounds__(256) void c_gemm(
    const float* __restrict__ Ab, const float* __restrict__ RHb,
    const float* __restrict__ ww, const float* __restrict__ uu,
    const float* __restrict__ bw, const float* __restrict__ bu,
    float* __restrict__ Zb, const float* __restrict__ Hb) {
    __shared__ float xa[16][68], xr[16][68], wls[2][16][68];
    int t = threadIdx.x;
    int m_base = blockIdx.x * 64;
    int n_base = blockIdx.y * 64;
    int lr = t >> 2, lk = (t & 3) * 4;
    int tn = t & 15, tm = t >> 4;
    int m0 = tm * 4, n0 = tn * 4;
    float acc[4][4] = {};
    size_t xoff = (size_t)(m_base + lr) * HDIM + lk;
    size_t woff = (size_t)(n_base + lr) * HDIM + lk;
    for (int kc = 0; kc < 512; kc += 16) {
        float4 va = *(const float4*)&Ab[xoff + kc];
        float4 vr = *(const float4*)&RHb[xoff + kc];
        float4 v0 = *(const float4*)&ww[woff + kc];
        float4 v1 = *(const float4*)&uu[woff + kc];
        __syncthreads();
        {
            const float* p;
            p = (const float*)&va;
#pragma unroll
            for (int u = 0; u < 4; ++u) xa[lk + u][lr] = p[u];
            p = (const float*)&vr;
#pragma unroll
            for (int u = 0; u < 4; ++u) xr[lk + u][lr] = p[u];
            p = (const float*)&v0;
#pragma unroll
            for (int u = 0; u < 4; ++u) wls[0][lk + u][lr] = p[u];
            p = (const float*)&v1;
#pragma unroll
            for (int u = 0; u < 4; ++u) wls[1][lk + u][lr] = p[u];
        }
        __syncthreads();
#pragma unroll
        for (int kk = 0; kk < 16; ++kk) {
            float4 a4 = *(float4*)&xa[kk][m0];
            float4 r4 = *(float4*)&xr[kk][m0];
            float4 w4 = *(float4*)&wls[0][kk][n0];
            float4 u4 = *(float4*)&wls[1][kk][n0];
            float aa[4] = {a4.x, a4.y, a4.z, a4.w};
            float rr[4] = {r4.x, r4.y, r4.z, r4.w};
            float wv[4] = {w4.x, w4.y, w4.z, w4.w};
            float uv[4] = {u4.x, u4.y, u4.z, u4.w};
#pragma unroll
            for (int i = 0; i < 4; ++i)
#pragma unroll
                for (int j = 0; j < 4; ++j)
                    acc[i][j] = fmaf(aa[i], wv[j], fmaf(rr[i], uv[j], acc[i][j]));
        }
    }
#pragma unroll
    for (int i = 0; i < 4; ++i) {
        int m = m_base + m0 + i;
        int n = n_base + n0;
        float4 hq = *(const float4*)&Hb[(size_t)m * HDIM + n];
        float4 zq = *(const float4*)&Zb[(size_t)m * HDIM + n];
        float hh[4] = {hq.x, hq.y, hq.z, hq.w};
        float zz[4] = {zq.x, zq.y, zq.z, zq.w};
        float ho[4];
#pragma unroll
        for (int j = 0; j < 4; ++j) {
            float cc = acc[i][j] + bw[n + j] + bu[n + j];
            float x = cc > 15.0f ? 15.0f : (cc < -15.0f ? -15.0f : cc);
            float e = __expf(2.0f * x);
            float cv = (e - 1.0f) / (e + 1.0f);
            ho[j] = (1.0f - zz[j]) * hh[j] + zz[j] * cv;
        }
        *(float4*)&Zb[(size_t)m * HDIM + n] = make_float4(ho[0], ho[1], ho[2], ho[3]);
    }
}

// ---------------- transpose small weight (256,512) -> (512,256) ----------------
__global__ __launch_bounds__(256) void transpose_w(const float* __restrict__ w, float* __restrict__ wt) {
    int idx = blockIdx.x * 256 + threadIdx.x;   // 131072
    int k = idx >> 8, n = idx & 255;
    wt[idx] = w[n * 512 + k];
}

// ---------------- fused scorer MLP: out[m] = relu(b2 + sum_n wsm[n]*relu(sum_k X[m,k]*W[n,k] + b1[n]))
// X row m (chunk-local) maps to h row (m/inner)*13 + off + (m%inner). 32 rows/block.
__global__ __launch_bounds__(256) void score_mlp(
    const float* __restrict__ H, const float* __restrict__ WT,  // WT: (512,256) k-major
    const float* __restrict__ bias1, const float* __restrict__ wsm,
    const float* __restrict__ bias2, float* __restrict__ outv, int inner, int off) {
    __shared__ float xs[16][36];
    __shared__ float wsb[16][260];
    __shared__ float red[32][33];
    int t = threadIdx.x;
    int mb = blockIdx.x * 32;
    int rr = t >> 3;
    int kq = (t & 7) * 2;
    int mrow = mb + rr;
    int src = (mrow / inner) * 13 + off + (mrow % inner);
    int tn = t & 31, tm = t >> 5;
    int n0 = tn * 8, m0 = tm * 4;
    int nw4 = (t & 63) * 4;
    int kr = t >> 6;
    float acc[4][8] = {};
    for (int kc = 0; kc < 512; kc += 16) {
        float2 xv = *(const float2*)&H[(size_t)src * HDIM + kc + kq];
        float4 wv[4];
#pragma unroll
        for (int u = 0; u < 4; ++u) wv[u] = *(const float4*)&WT[(kc + kr * 4 + u) * 256 + nw4];
        __syncthreads();
        xs[kq][rr] = xv.x;
        xs[kq + 1][rr] = xv.y;
#pragma unroll
        for (int u = 0; u < 4; ++u) *(float4*)&wsb[kr * 4 + u][nw4] = wv[u];
        __syncthreads();
#pragma unroll
        for (int kk = 0; kk < 16; ++kk) {
            float4 x4 = *(float4*)&xs[kk][m0];
            float4 w0 = *(float4*)&wsb[kk][n0];
            float4 w1v = *(float4*)&wsb[kk][n0 + 4];
            float xx[4] = {x4.x, x4.y, x4.z, x4.w};
            float wa[8] = {w0.x, w0.y, w0.z, w0.w, w1v.x, w1v.y, w1v.z, w1v.w};
#pragma unroll
            for (int i = 0; i < 4; ++i)
#pragma unroll
                for (int j = 0; j < 8; ++j) acc[i][j] = fmaf(xx[i], wa[j], acc[i][j]);
        }
    }
    float part[4];
#pragma unroll
    for (int i = 0; i < 4; ++i) {
        float s = 0.0f;
#pragma unroll
        for (int j = 0; j < 8; ++j) {
            int n = n0 + j;
            float v = acc[i][j] + bias1[n];
            v = v > 0.0f ? v : 0.0f;
            s = fmaf(v, wsm[n], s);
        }
        part[i] = s;
    }
    __syncthreads();
#pragma unroll
    for (int i = 0; i < 4; ++i) red[m0 + i][tn] = part[i];
    __syncthreads();
    if (t < 32) {
        float s = 0.0f;
#pragma unroll
        for (int q = 0; q < 32; ++q) s += red[t][q];
        s += bias2[0];
        outv[mb + t] = s > 0.0f ? s : 0.0f;
    }
}

// ---------------- final: softmax weights over 8 ctx nodes, weighted sum, -L2 distance ----------------
__global__ __launch_bounds__(256) void final_kernel(const float* __restrict__ H,
                                                    const float* __restrict__ UAv,
                                                    const float* __restrict__ UBv,
                                                    float* __restrict__ outv) {
    int b = blockIdx.x;
    int t = threadIdx.x;
    __shared__ float ctx[8][512];
    __shared__ float uas[8], ubs[5];
    __shared__ float red[4];
#pragma unroll
    for (int q = 0; q < 16; ++q) {
        int idx = q * 256 + t;
        int j = idx >> 9, c = idx & 511;
        ctx[j][c] = H[(size_t)(b * 13 + j) * HDIM + c];
    }
    if (t < 8) uas[t] = UAv[b * 8 + t];
    if (t < 5) ubs[t] = UBv[b * 5 + t];
    __syncthreads();
    int c0 = t, c1 = t + 256;
    int wid = t >> 6, lane = t & 63;
    for (int s = 0; s < 5; ++s) {
        float wn[8];
        float sum = 0.0f;
#pragma unroll
        for (int j = 0; j < 8; ++j) {
            wn[j] = __expf(tanhf(uas[j] + ubs[s]));
            sum += wn[j];
        }
        float inv = 1.0f / sum;
        float av0 = 0.0f, av1 = 0.0f;
#pragma unroll
        for (int j = 0; j < 8; ++j) {
            av0 = fmaf(wn[j], ctx[j][c0], av0);
            av1 = fmaf(wn[j], ctx[j][c1], av1);
        }
        av0 *= inv;
        av1 *= inv;
        float d0 = av0 - H[(size_t)(b * 13 + 8 + s) * HDIM + c0];
        float d1 = av1 - H[(size_t)(b * 13 + 8 + s) * HDIM + c1];
        float v = d0 * d0 + d1 * d1;
#pragma unroll
        for (int o = 32; o > 0; o >>= 1) v += __shfl_down(v, o);
        if (lane == 0) red[wid] = v;
        __syncthreads();
        if (t == 0) outv[b * 5 + s] = -sqrtf(red[0] + red[1] + red[2] + red[3]);
        __syncthreads();
    }
}

extern "C" void kernel_launch(void* const* d_in, const int* in_sizes, int n_in,
                              void* d_out, int out_size, void* d_ws, size_t ws_size,
                              hipStream_t stream) {
    const float* Ain  = (const float*)d_in[0];
    const int*   ids  = (const int*)d_in[1];
    const float* emb  = (const float*)d_in[2];
    const float* b_ah = (const float*)d_in[3];
    const float* w_z  = (const float*)d_in[4];
    const float* b_wz = (const float*)d_in[5];
    const float* u_z  = (const float*)d_in[6];
    const float* b_uz = (const float*)d_in[7];
    const float* w_r  = (const float*)d_in[8];
    const float* b_wr = (const float*)d_in[9];
    const float* u_r  = (const float*)d_in[10];
    const float* b_ur = (const float*)d_in[11];
    const float* w_   = (const float*)d_in[12];
    const float* b_w  = (const float*)d_in[13];
    const float* u_u  = (const float*)d_in[14];
    const float* b_u  = (const float*)d_in[15];
    const float* w1   = (const float*)d_in[16];
    const float* b1   = (const float*)d_in[17];
    const float* w12  = (const float*)d_in[18];
    const float* b12  = (const float*)d_in[19];
    const float* w2   = (const float*)d_in[20];
    const float* b2   = (const float*)d_in[21];
    const float* w22  = (const float*)d_in[22];
    const float* b22  = (const float*)d_in[23];
    float* out = (float*)d_out;

    // ---- choose chunk size (graphs per chunk) from ws_size; deterministic ----
    // footprint(C) = 4 big fp32 buffers of (13C x 512) + UA(8C) + UB(5C) + 2 transposed weights + slack
    int C = 64;
    {
        const int cands[7] = {4096, 2048, 1024, 512, 256, 128, 64};
        for (int ci = 0; ci < 7; ++ci) {
            int cc = cands[ci];
            size_t rows = (size_t)13 * cc;
            size_t need = 4 * rows * 512 * sizeof(float)
                        + (size_t)13 * cc * sizeof(float)
                        + 2 * (size_t)131072 * sizeof(float)
                        + (1u << 20);
            if (need <= ws_size) { C = cc; break; }
        }
    }
    const int rows = 13 * C;

    float* ws  = (float*)d_ws;
    float* W1T = ws;
    float* W2T = W1T + 131072;
    float* UA  = W2T + 131072;
    float* UB  = UA + 8 * C;
    float* H0  = UB + 5 * C;
    float* B1  = H0 + (size_t)rows * 512;
    float* AB  = B1 + (size_t)rows * 512;
    float* RH  = AB + (size_t)rows * 512;

    transpose_w<<<512, 256, 0, stream>>>(w1, W1T);
    transpose_w<<<512, 256, 0, stream>>>(w2, W2T);

    for (int g0 = 0; g0 < 4096; g0 += C) {
        gather_kernel<<<rows, 512, 0, stream>>>(ids + (size_t)g0 * 52, emb, H0);
        float* hc = H0;
        float* hn = B1;
        for (int it = 0; it < 2; ++it) {
            a_kernel<<<C, 512, 0, stream>>>(Ain + (size_t)g0 * 169, hc, b_ah, AB);
            zr_gemm<<<dim3(rows / 64, 8), 256, 0, stream>>>(AB, hc, w_z, u_z, w_r, u_r,
                                                            b_wz, b_uz, b_wr, b_ur, hn, RH);
            c_gemm<<<dim3(rows / 64, 8), 256, 0, stream>>>(AB, RH, w_, u_u, b_w, b_u, hn, hc);
            float* tmp = hc; hc = hn; hn = tmp;
        }
        // hc holds final h for this chunk
        score_mlp<<<C * 8 / 32, 256, 0, stream>>>(hc, W1T, b1, w12, b12, UA, 8, 0);
        score_mlp<<<C * 5 / 32, 256, 0, stream>>>(hc, W2T, b2, w22, b22, UB, 5, 8);
        final_kernel<<<C, 256, 0, stream>>>(hc, UA, UB, out + (size_t)g0 * 5);
    }
}

// Round 3
// 1463.761 us; speedup vs baseline: 3.2360x; 3.2360x over previous
//
#include <hip/hip_runtime.h>
#include <hip/hip_bf16.h>
#include <math.h>

#define HDIM 512

typedef __attribute__((ext_vector_type(8))) __bf16 bf16x8;
typedef __attribute__((ext_vector_type(4))) float f32x4;

__device__ __forceinline__ float sigmoidf_(float x) { return 1.0f / (1.0f + __expf(-x)); }

// ---------------- fp32 -> bf16 copy (weights) ----------------
__global__ __launch_bounds__(256) void f2bf(const float* __restrict__ s, __bf16* __restrict__ d, int n) {
    int i = blockIdx.x * 256 + threadIdx.x;
    int stride = gridDim.x * 256;
    for (; i < n; i += stride) d[i] = (__bf16)s[i];
}

// ---------------- gather: h0 fp32 + bf16 ----------------
__global__ __launch_bounds__(512) void gather_kernel(const int* __restrict__ ids,
                                                     const float* __restrict__ emb,
                                                     float* __restrict__ Hf,
                                                     __bf16* __restrict__ Hbf) {
    int bj = blockIdx.x;            // chunk-local b*13 + j
    int b = bj / 13, j = bj - b * 13;
    int c = threadIdx.x;
    int i = c >> 7, e = c & 127;
    int id = ids[b * 52 + i * 13 + j];
    float v = emb[(size_t)id * 128 + e];
    Hf[(size_t)bj * HDIM + c] = v;
    Hbf[(size_t)bj * HDIM + c] = (__bf16)v;
}

// ---------------- a = At @ h + b_ah (per-graph 13x13 bmm) -> bf16 (GEMM operand only) ----------------
__global__ __launch_bounds__(512) void a_kernel(const float* __restrict__ Ain,
                                                const float* __restrict__ Hf,
                                                const float* __restrict__ bah,
                                                __bf16* __restrict__ Abf) {
    int b = blockIdx.x;
    int c = threadIdx.x;
    __shared__ float As[169];
    if (c < 169) As[c] = Ain[b * 169 + c];
    float hreg[13];
#pragma unroll
    for (int j = 0; j < 13; ++j) hreg[j] = Hf[(size_t)(b * 13 + j) * HDIM + c];
    __syncthreads();
    float bb = bah[c];
#pragma unroll
    for (int i = 0; i < 13; ++i) {
        float acc = bb;
#pragma unroll
        for (int j = 0; j < 13; ++j) acc = fmaf(As[j * 13 + i], hreg[j], acc);
        Abf[(size_t)(b * 13 + i) * HDIM + c] = (__bf16)acc;
    }
}

// ---------------- MFMA GEMM: acc = X1@W1^T + X2@W2^T  (M=13C, N=512, K=512+512)
// 128x128 tile, BK=32, 256 threads = 4 waves (2x2), each wave 64x64 (4x4 frags of 16x16).
// mode 0: Zf = sigmoid(acc + b1 + b2)
// mode 1: RHbf = bf16( sigmoid(acc + b1 + b2) * Hf )
// mode 2: c = tanh(acc + b1 + b2); hn = (1-z)h + z*c -> HfOut (f32), HbfOut (bf16)
__global__ __launch_bounds__(256) void gemm2_mfma(
    const __bf16* __restrict__ X1, const __bf16* __restrict__ X2,
    const __bf16* __restrict__ W1, const __bf16* __restrict__ W2,
    const float* __restrict__ b1, const float* __restrict__ b2,
    const float* __restrict__ Hf, float* __restrict__ Zf,
    __bf16* __restrict__ RHbf, float* __restrict__ HfOut, __bf16* __restrict__ HbfOut,
    int mode) {
    __shared__ __bf16 lA[128 * 32];
    __shared__ __bf16 lB[128 * 32];
    int t = threadIdx.x;
    int w = t >> 6, lane = t & 63;
    int wr = w >> 1, wc = w & 1;
    int m_base = blockIdx.x * 128;
    int n_base = blockIdx.y * 128;

    f32x4 acc[4][4];
#pragma unroll
    for (int i = 0; i < 4; ++i)
#pragma unroll
        for (int j = 0; j < 4; ++j)
#pragma unroll
            for (int q = 0; q < 4; ++q) acc[i][j][q] = 0.0f;

    // staging geometry: thread covers 16B = 8 bf16 at tile elem (u*2048 + w*512 + lane*8)
    int srow = (w << 4) + (lane >> 2);   // + u*64
    int skk = (lane & 3) << 3;
    int frow = lane & 15, kg = lane >> 4;

    const __bf16* Xseg[2] = {X1, X2};
    const __bf16* Wseg[2] = {W1, W2};

    for (int s = 0; s < 2; ++s) {
        const __bf16* Xp = Xseg[s];
        const __bf16* Wp = Wseg[s];
        for (int kc = 0; kc < 512; kc += 32) {
#pragma unroll
            for (int u = 0; u < 2; ++u) {
                int row = u * 64 + srow;
                const __bf16* ga = Xp + (size_t)(m_base + row) * HDIM + kc + skk;
                const __bf16* gb = Wp + (size_t)(n_base + row) * HDIM + kc + skk;
                __builtin_amdgcn_global_load_lds(
                    (const __attribute__((address_space(1))) void*)ga,
                    (__attribute__((address_space(3))) void*)&lA[u * 2048 + w * 512], 16, 0, 0);
                __builtin_amdgcn_global_load_lds(
                    (const __attribute__((address_space(1))) void*)gb,
                    (__attribute__((address_space(3))) void*)&lB[u * 2048 + w * 512], 16, 0, 0);
            }
            asm volatile("s_waitcnt vmcnt(0)" ::: "memory");
            __syncthreads();
            bf16x8 af[4], bfr[4];
#pragma unroll
            for (int i = 0; i < 4; ++i) {
                af[i] = *(const bf16x8*)&lA[(wr * 64 + i * 16 + frow) * 32 + kg * 8];
                bfr[i] = *(const bf16x8*)&lB[(wc * 64 + i * 16 + frow) * 32 + kg * 8];
            }
#pragma unroll
            for (int i = 0; i < 4; ++i)
#pragma unroll
                for (int j = 0; j < 4; ++j)
                    acc[i][j] = __builtin_amdgcn_mfma_f32_16x16x32_bf16(af[i], bfr[j], acc[i][j], 0, 0, 0);
            __syncthreads();
        }
    }

    // epilogue: D[row = (lane>>4)*4 + q][col = lane&15] per 16x16 frag
    int frow4 = (lane >> 4) * 4;
    int fcol = lane & 15;
#pragma unroll
    for (int i = 0; i < 4; ++i) {
#pragma unroll
        for (int j = 0; j < 4; ++j) {
            int col = n_base + wc * 64 + j * 16 + fcol;
            float bias = b1[col] + b2[col];
            int rbase = m_base + wr * 64 + i * 16 + frow4;
#pragma unroll
            for (int q = 0; q < 4; ++q) {
                size_t off = (size_t)(rbase + q) * HDIM + col;
                float v = acc[i][j][q] + bias;
                if (mode == 0) {
                    Zf[off] = sigmoidf_(v);
                } else if (mode == 1) {
                    RHbf[off] = (__bf16)(sigmoidf_(v) * Hf[off]);
                } else {
                    float x = v > 15.0f ? 15.0f : (v < -15.0f ? -15.0f : v);
                    float e = __expf(2.0f * x);
                    float cv = (e - 1.0f) / (e + 1.0f);
                    float h = Hf[off], z = Zf[off];
                    float hn = (1.0f - z) * h + z * cv;
                    HfOut[off] = hn;
                    HbfOut[off] = (__bf16)hn;
                }
            }
        }
    }
}

// ---------------- transpose small weight (256,512) -> (512,256) ----------------
__global__ __launch_bounds__(256) void transpose_w(const float* __restrict__ w, float* __restrict__ wt) {
    int idx = blockIdx.x * 256 + threadIdx.x;   // 131072
    int k = idx >> 8, n = idx & 255;
    wt[idx] = w[n * 512 + k];
}

// ---------------- fused scorer MLP (fp32) ----------------
__global__ __launch_bounds__(256) void score_mlp(
    const float* __restrict__ H, const float* __restrict__ WT,
    const float* __restrict__ bias1, const float* __restrict__ wsm,
    const float* __restrict__ bias2, float* __restrict__ outv, int inner, int off) {
    __shared__ float xs[16][36];
    __shared__ float wsb[16][260];
    __shared__ float red[32][33];
    int t = threadIdx.x;
    int mb = blockIdx.x * 32;
    int rr = t >> 3;
    int kq = (t & 7) * 2;
    int mrow = mb + rr;
    int src = (mrow / inner) * 13 + off + (mrow % inner);
    int tn = t & 31, tm = t >> 5;
    int n0 = tn * 8, m0 = tm * 4;
    int nw4 = (t & 63) * 4;
    int kr = t >> 6;
    float acc[4][8] = {};
    for (int kc = 0; kc < 512; kc += 16) {
        float2 xv = *(const float2*)&H[(size_t)src * HDIM + kc + kq];
        float4 wv[4];
#pragma unroll
        for (int u = 0; u < 4; ++u) wv[u] = *(const float4*)&WT[(kc + kr * 4 + u) * 256 + nw4];
        __syncthreads();
        xs[kq][rr] = xv.x;
        xs[kq + 1][rr] = xv.y;
#pragma unroll
        for (int u = 0; u < 4; ++u) *(float4*)&wsb[kr * 4 + u][nw4] = wv[u];
        __syncthreads();
#pragma unroll
        for (int kk = 0; kk < 16; ++kk) {
            float4 x4 = *(float4*)&xs[kk][m0];
            float4 w0 = *(float4*)&wsb[kk][n0];
            float4 w1v = *(float4*)&wsb[kk][n0 + 4];
            float xx[4] = {x4.x, x4.y, x4.z, x4.w};
            float wa[8] = {w0.x, w0.y, w0.z, w0.w, w1v.x, w1v.y, w1v.z, w1v.w};
#pragma unroll
            for (int i = 0; i < 4; ++i)
#pragma unroll
                for (int j = 0; j < 8; ++j) acc[i][j] = fmaf(xx[i], wa[j], acc[i][j]);
        }
    }
    float part[4];
#pragma unroll
    for (int i = 0; i < 4; ++i) {
        float s = 0.0f;
#pragma unroll
        for (int j = 0; j < 8; ++j) {
            int n = n0 + j;
            float v = acc[i][j] + bias1[n];
            v = v > 0.0f ? v : 0.0f;
            s = fmaf(v, wsm[n], s);
        }
        part[i] = s;
    }
    __syncthreads();
#pragma unroll
    for (int i = 0; i < 4; ++i) red[m0 + i][tn] = part[i];
    __syncthreads();
    if (t < 32) {
        float s = 0.0f;
#pragma unroll
        for (int q = 0; q < 32; ++q) s += red[t][q];
        s += bias2[0];
        outv[mb + t] = s > 0.0f ? s : 0.0f;
    }
}

// ---------------- final: softmax over 8 ctx nodes, weighted sum, -L2 distance ----------------
__global__ __launch_bounds__(256) void final_kernel(const float* __restrict__ H,
                                                    const float* __restrict__ UAv,
                                                    const float* __restrict__ UBv,
                                                    float* __restrict__ outv) {
    int b = blockIdx.x;
    int t = threadIdx.x;
    __shared__ float ctx[8][512];
    __shared__ float uas[8], ubs[5];
    __shared__ float red[4];
#pragma unroll
    for (int q = 0; q < 16; ++q) {
        int idx = q * 256 + t;
        int j = idx >> 9, c = idx & 511;
        ctx[j][c] = H[(size_t)(b * 13 + j) * HDIM + c];
    }
    if (t < 8) uas[t] = UAv[b * 8 + t];
    if (t < 5) ubs[t] = UBv[b * 5 + t];
    __syncthreads();
    int c0 = t, c1 = t + 256;
    int wid = t >> 6, lane = t & 63;
    for (int s = 0; s < 5; ++s) {
        float wn[8];
        float sum = 0.0f;
#pragma unroll
        for (int j = 0; j < 8; ++j) {
            wn[j] = __expf(tanhf(uas[j] + ubs[s]));
            sum += wn[j];
        }
        float inv = 1.0f / sum;
        float av0 = 0.0f, av1 = 0.0f;
#pragma unroll
        for (int j = 0; j < 8; ++j) {
            av0 = fmaf(wn[j], ctx[j][c0], av0);
            av1 = fmaf(wn[j], ctx[j][c1], av1);
        }
        av0 *= inv;
        av1 *= inv;
        float d0 = av0 - H[(size_t)(b * 13 + 8 + s) * HDIM + c0];
        float d1 = av1 - H[(size_t)(b * 13 + 8 + s) * HDIM + c1];
        float v = d0 * d0 + d1 * d1;
#pragma unroll
        for (int o = 32; o > 0; o >>= 1) v += __shfl_down(v, o);
        if (lane == 0) red[wid] = v;
        __syncthreads();
        if (t == 0) outv[b * 5 + s] = -sqrtf(red[0] + red[1] + red[2] + red[3]);
        __syncthreads();
    }
}

extern "C" void kernel_launch(void* const* d_in, const int* in_sizes, int n_in,
                              void* d_out, int out_size, void* d_ws, size_t ws_size,
                              hipStream_t stream) {
    const float* Ain  = (const float*)d_in[0];
    const int*   ids  = (const int*)d_in[1];
    const float* emb  = (const float*)d_in[2];
    const float* b_ah = (const float*)d_in[3];
    const float* w_z  = (const float*)d_in[4];
    const float* b_wz = (const float*)d_in[5];
    const float* u_z  = (const float*)d_in[6];
    const float* b_uz = (const float*)d_in[7];
    const float* w_r  = (const float*)d_in[8];
    const float* b_wr = (const float*)d_in[9];
    const float* u_r  = (const float*)d_in[10];
    const float* b_ur = (const float*)d_in[11];
    const float* w_   = (const float*)d_in[12];
    const float* b_w  = (const float*)d_in[13];
    const float* u_u  = (const float*)d_in[14];
    const float* b_u  = (const float*)d_in[15];
    const float* w1   = (const float*)d_in[16];
    const float* b1   = (const float*)d_in[17];
    const float* w12  = (const float*)d_in[18];
    const float* b12  = (const float*)d_in[19];
    const float* w2   = (const float*)d_in[20];
    const float* b2   = (const float*)d_in[21];
    const float* w22  = (const float*)d_in[22];
    const float* b22  = (const float*)d_in[23];
    float* out = (float*)d_out;

    // ---- chunk size: need rows=13C divisible by 128 -> C multiple of 128 ----
    // footprint: Hf(4) + Zf(4) + Abf(2) + Hbf(2) + RHbf(2) = 14B per (rows x 512) elem
    int C = 128;
    {
        const int cands[6] = {4096, 2048, 1024, 512, 256, 128};
        for (int ci = 0; ci < 6; ++ci) {
            int cc = cands[ci];
            size_t rows = (size_t)13 * cc;
            size_t need = rows * 512 * 14
                        + 6 * (size_t)262144 * 2      // bf16 weights
                        + 2 * (size_t)131072 * 4      // W1T/W2T
                        + (size_t)13 * cc * 4         // UA+UB
                        + (4u << 20);
            if (need <= ws_size) { C = cc; break; }
        }
    }
    const int rows = 13 * C;

    char* base = (char*)d_ws;
    __bf16* Wzb = (__bf16*)base; base += 262144 * 2;
    __bf16* Uzb = (__bf16*)base; base += 262144 * 2;
    __bf16* Wrb = (__bf16*)base; base += 262144 * 2;
    __bf16* Urb = (__bf16*)base; base += 262144 * 2;
    __bf16* Wb  = (__bf16*)base; base += 262144 * 2;
    __bf16* Ub  = (__bf16*)base; base += 262144 * 2;
    float* W1T = (float*)base; base += 131072 * 4;
    float* W2T = (float*)base; base += 131072 * 4;
    float* UA  = (float*)base; base += (size_t)8 * C * 4;
    float* UB  = (float*)base; base += (size_t)5 * C * 4;
    float* Hf  = (float*)base; base += (size_t)rows * 512 * 4;
    float* Zf  = (float*)base; base += (size_t)rows * 512 * 4;
    __bf16* Hbf  = (__bf16*)base; base += (size_t)rows * 512 * 2;
    __bf16* Abf  = (__bf16*)base; base += (size_t)rows * 512 * 2;
    __bf16* RHbf = (__bf16*)base; base += (size_t)rows * 512 * 2;

    f2bf<<<128, 256, 0, stream>>>(w_z, Wzb, 262144);
    f2bf<<<128, 256, 0, stream>>>(u_z, Uzb, 262144);
    f2bf<<<128, 256, 0, stream>>>(w_r, Wrb, 262144);
    f2bf<<<128, 256, 0, stream>>>(u_r, Urb, 262144);
    f2bf<<<128, 256, 0, stream>>>(w_, Wb, 262144);
    f2bf<<<128, 256, 0, stream>>>(u_u, Ub, 262144);
    transpose_w<<<512, 256, 0, stream>>>(w1, W1T);
    transpose_w<<<512, 256, 0, stream>>>(w2, W2T);

    dim3 ggrid(rows / 128, 4);
    for (int g0 = 0; g0 < 4096; g0 += C) {
        gather_kernel<<<rows, 512, 0, stream>>>(ids + (size_t)g0 * 52, emb, Hf, Hbf);
        for (int it = 0; it < 2; ++it) {
            a_kernel<<<C, 512, 0, stream>>>(Ain + (size_t)g0 * 169, Hf, b_ah, Abf);
            gemm2_mfma<<<ggrid, 256, 0, stream>>>(Abf, Hbf, Wzb, Uzb, b_wz, b_uz,
                                                  nullptr, Zf, nullptr, nullptr, nullptr, 0);
            gemm2_mfma<<<ggrid, 256, 0, stream>>>(Abf, Hbf, Wrb, Urb, b_wr, b_ur,
                                                  Hf, nullptr, RHbf, nullptr, nullptr, 1);
            gemm2_mfma<<<ggrid, 256, 0, stream>>>(Abf, RHbf, Wb, Ub, b_w, b_u,
                                                  Hf, Zf, nullptr, Hf, Hbf, 2);
        }
        score_mlp<<<C * 8 / 32, 256, 0, stream>>>(Hf, W1T, b1, w12, b12, UA, 8, 0);
        score_mlp<<<C * 5 / 32, 256, 0, stream>>>(Hf, W2T, b2, w22, b22, UB, 5, 8);
        final_kernel<<<C, 256, 0, stream>>>(Hf, UA, UB, out + (size_t)g0 * 5);
    }
}

// Round 4
// 1264.803 us; speedup vs baseline: 3.7451x; 1.1573x over previous
//
#include <hip/hip_runtime.h>
#include <hip/hip_bf16.h>
#include <math.h>

#define HDIM 512

typedef __attribute__((ext_vector_type(8))) __bf16 bf16x8;
typedef __attribute__((ext_vector_type(4))) float f32x4;

__device__ __forceinline__ float sigmoidf_(float x) { return 1.0f / (1.0f + __expf(-x)); }

// ---------------- fp32 -> bf16 copy (weights) ----------------
__global__ __launch_bounds__(256) void f2bf(const float* __restrict__ s, __bf16* __restrict__ d, int n) {
    int i = blockIdx.x * 256 + threadIdx.x;
    int stride = gridDim.x * 256;
    for (; i < n; i += stride) d[i] = (__bf16)s[i];
}

// ---------------- gather: h0 fp32 + bf16 ----------------
__global__ __launch_bounds__(512) void gather_kernel(const int* __restrict__ ids,
                                                     const float* __restrict__ emb,
                                                     float* __restrict__ Hf,
                                                     __bf16* __restrict__ Hbf) {
    int bj = blockIdx.x;            // chunk-local b*13 + j
    int b = bj / 13, j = bj - b * 13;
    int c = threadIdx.x;
    int i = c >> 7, e = c & 127;
    int id = ids[b * 52 + i * 13 + j];
    float v = emb[(size_t)id * 128 + e];
    Hf[(size_t)bj * HDIM + c] = v;
    Hbf[(size_t)bj * HDIM + c] = (__bf16)v;
}

// ---------------- a = At @ h + b_ah (per-graph 13x13 bmm), bf16 h input ----------------
__global__ __launch_bounds__(512) void a_kernel(const float* __restrict__ Ain,
                                                const __bf16* __restrict__ Hbf,
                                                const float* __restrict__ bah,
                                                __bf16* __restrict__ Abf) {
    int b = blockIdx.x;
    int c = threadIdx.x;
    __shared__ float As[169];
    if (c < 169) As[c] = Ain[b * 169 + c];
    float hreg[13];
#pragma unroll
    for (int j = 0; j < 13; ++j) hreg[j] = (float)Hbf[(size_t)(b * 13 + j) * HDIM + c];
    __syncthreads();
    float bb = bah[c];
#pragma unroll
    for (int i = 0; i < 13; ++i) {
        float acc = bb;
#pragma unroll
        for (int j = 0; j < 13; ++j) acc = fmaf(As[j * 13 + i], hreg[j], acc);
        Abf[(size_t)(b * 13 + i) * HDIM + c] = (__bf16)acc;
    }
}

// ================= fused z+r GEMM =================
// 512 threads = 8 waves. Wave w: role=(w&1) (0:z, 1:r), pos wq=w>>1 -> (wr2,wc2) in 2x2.
// Tile 128x128, BK=32, K = 512(a-side) + 512(h-side).
// z = sigmoid(a@wz^T + h@uz^T + bz);  rh = bf16( sigmoid(a@wr^T + h@ur^T + br) * h )
// LDS swizzle (both-sides involution): slot' = slot ^ ((row>>1)&3), 16B slots, row stride 64B.
__global__ __launch_bounds__(512) void zr_fused(
    const __bf16* __restrict__ Abf, const __bf16* __restrict__ Hbf,
    const __bf16* __restrict__ Wz, const __bf16* __restrict__ Uz,
    const __bf16* __restrict__ Wr, const __bf16* __restrict__ Ur,
    const float* __restrict__ bwz, const float* __restrict__ buz,
    const float* __restrict__ bwr, const float* __restrict__ bur,
    float* __restrict__ Zf, __bf16* __restrict__ RHbf) {
    __shared__ __bf16 lA[4096];      // 128 x 32
    __shared__ __bf16 lB[2][4096];   // [role][128 x 32]
    int t = threadIdx.x;
    int w = t >> 6, lane = t & 63;
    int role = w & 1;
    int wq = w >> 1;
    int wr2 = wq >> 1, wc2 = wq & 1;
    int m_base = blockIdx.x * 128;
    int n_base = blockIdx.y * 128;

    f32x4 acc[4][4];
#pragma unroll
    for (int i = 0; i < 4; ++i)
#pragma unroll
        for (int j = 0; j < 4; ++j)
#pragma unroll
            for (int q = 0; q < 4; ++q) acc[i][j][q] = 0.0f;

    // staging: thread t covers LDS row=t>>2, phys slot=t&3 (16B). source slot pre-swizzled.
    int srow = t >> 2;
    int sslot = (t & 3) ^ ((t >> 3) & 3);
    int scol = sslot << 3;           // bf16 col within 32
    // per-wave LDS dest base (wave-uniform) + lane*16
    int frow = lane & 15, kg = lane >> 4;
    int rsl = kg ^ ((frow >> 1) & 3);

    const __bf16* Xseg[2] = {Abf, Hbf};
    const __bf16* Bseg[2][2] = {{Wz, Wr}, {Uz, Ur}};

    for (int s = 0; s < 2; ++s) {
        const __bf16* Xp = Xseg[s];
        const __bf16* Bz = Bseg[s][0];
        const __bf16* Br = Bseg[s][1];
        for (int kc = 0; kc < 512; kc += 32) {
            const __bf16* ga = Xp + (size_t)(m_base + srow) * HDIM + kc + scol;
            const __bf16* gz = Bz + (size_t)(n_base + srow) * HDIM + kc + scol;
            const __bf16* gr = Br + (size_t)(n_base + srow) * HDIM + kc + scol;
            __builtin_amdgcn_global_load_lds(
                (const __attribute__((address_space(1))) void*)ga,
                (__attribute__((address_space(3))) void*)&lA[w * 512], 16, 0, 0);
            __builtin_amdgcn_global_load_lds(
                (const __attribute__((address_space(1))) void*)gz,
                (__attribute__((address_space(3))) void*)&lB[0][w * 512], 16, 0, 0);
            __builtin_amdgcn_global_load_lds(
                (const __attribute__((address_space(1))) void*)gr,
                (__attribute__((address_space(3))) void*)&lB[1][w * 512], 16, 0, 0);
            asm volatile("s_waitcnt vmcnt(0)" ::: "memory");
            __syncthreads();
            bf16x8 af[4], bfr[4];
#pragma unroll
            for (int i = 0; i < 4; ++i) {
                af[i] = *(const bf16x8*)&lA[(wr2 * 64 + i * 16 + frow) * 32 + rsl * 8];
                bfr[i] = *(const bf16x8*)&lB[role][(wc2 * 64 + i * 16 + frow) * 32 + rsl * 8];
            }
#pragma unroll
            for (int i = 0; i < 4; ++i)
#pragma unroll
                for (int j = 0; j < 4; ++j)
                    acc[i][j] = __builtin_amdgcn_mfma_f32_16x16x32_bf16(af[i], bfr[j], acc[i][j], 0, 0, 0);
            __syncthreads();
        }
    }

    int frow4 = (lane >> 4) * 4;
    int fcol = lane & 15;
#pragma unroll
    for (int i = 0; i < 4; ++i) {
#pragma unroll
        for (int j = 0; j < 4; ++j) {
            int col = n_base + wc2 * 64 + j * 16 + fcol;
            float bias = role ? (bwr[col] + bur[col]) : (bwz[col] + buz[col]);
            int rbase = m_base + wr2 * 64 + i * 16 + frow4;
#pragma unroll
            for (int q = 0; q < 4; ++q) {
                size_t off = (size_t)(rbase + q) * HDIM + col;
                float v = sigmoidf_(acc[i][j][q] + bias);
                if (role) {
                    RHbf[off] = (__bf16)(v * (float)Hbf[off]);
                } else {
                    Zf[off] = v;
                }
            }
        }
    }
}

// ================= c GEMM + gated update =================
// 256 threads = 4 waves (2x2), tile 128x128, BK=32, K=1024.
// c = tanh(a@w^T + rh@u_^T + b); hn = (1-z)h + z*c -> Hf, Hbf
__global__ __launch_bounds__(256) void c_fused(
    const __bf16* __restrict__ Abf, const __bf16* __restrict__ RHbf,
    const __bf16* __restrict__ W, const __bf16* __restrict__ U,
    const float* __restrict__ bw, const float* __restrict__ bu,
    const float* __restrict__ Zf, float* __restrict__ Hf, __bf16* __restrict__ Hbf) {
    __shared__ __bf16 lA[4096];
    __shared__ __bf16 lB[4096];
    int t = threadIdx.x;
    int w = t >> 6, lane = t & 63;
    int wr = w >> 1, wc = w & 1;
    int m_base = blockIdx.x * 128;
    int n_base = blockIdx.y * 128;

    f32x4 acc[4][4];
#pragma unroll
    for (int i = 0; i < 4; ++i)
#pragma unroll
        for (int j = 0; j < 4; ++j)
#pragma unroll
            for (int q = 0; q < 4; ++q) acc[i][j][q] = 0.0f;

    int srow = (w << 4) + (lane >> 2);   // +u*64
    int sslot = (lane & 3) ^ ((lane >> 3) & 3);
    int scol = sslot << 3;
    int frow = lane & 15, kg = lane >> 4;
    int rsl = kg ^ ((frow >> 1) & 3);

    const __bf16* Xseg[2] = {Abf, RHbf};
    const __bf16* Wseg[2] = {W, U};

    for (int s = 0; s < 2; ++s) {
        const __bf16* Xp = Xseg[s];
        const __bf16* Wp = Wseg[s];
        for (int kc = 0; kc < 512; kc += 32) {
#pragma unroll
            for (int u = 0; u < 2; ++u) {
                int row = u * 64 + srow;
                const __bf16* ga = Xp + (size_t)(m_base + row) * HDIM + kc + scol;
                const __bf16* gb = Wp + (size_t)(n_base + row) * HDIM + kc + scol;
                __builtin_amdgcn_global_load_lds(
                    (const __attribute__((address_space(1))) void*)ga,
                    (__attribute__((address_space(3))) void*)&lA[u * 2048 + w * 512], 16, 0, 0);
                __builtin_amdgcn_global_load_lds(
                    (const __attribute__((address_space(1))) void*)gb,
                    (__attribute__((address_space(3))) void*)&lB[u * 2048 + w * 512], 16, 0, 0);
            }
            asm volatile("s_waitcnt vmcnt(0)" ::: "memory");
            __syncthreads();
            bf16x8 af[4], bfr[4];
#pragma unroll
            for (int i = 0; i < 4; ++i) {
                af[i] = *(const bf16x8*)&lA[(wr * 64 + i * 16 + frow) * 32 + rsl * 8];
                bfr[i] = *(const bf16x8*)&lB[(wc * 64 + i * 16 + frow) * 32 + rsl * 8];
            }
#pragma unroll
            for (int i = 0; i < 4; ++i)
#pragma unroll
                for (int j = 0; j < 4; ++j)
                    acc[i][j] = __builtin_amdgcn_mfma_f32_16x16x32_bf16(af[i], bfr[j], acc[i][j], 0, 0, 0);
            __syncthreads();
        }
    }

    int frow4 = (lane >> 4) * 4;
    int fcol = lane & 15;
#pragma unroll
    for (int i = 0; i < 4; ++i) {
#pragma unroll
        for (int j = 0; j < 4; ++j) {
            int col = n_base + wc * 64 + j * 16 + fcol;
            float bias = bw[col] + bu[col];
            int rbase = m_base + wr * 64 + i * 16 + frow4;
#pragma unroll
            for (int q = 0; q < 4; ++q) {
                size_t off = (size_t)(rbase + q) * HDIM + col;
                float v = acc[i][j][q] + bias;
                float x = v > 15.0f ? 15.0f : (v < -15.0f ? -15.0f : v);
                float e = __expf(2.0f * x);
                float cv = (e - 1.0f) / (e + 1.0f);
                float h = Hf[off], z = Zf[off];
                float hn = (1.0f - z) * h + z * cv;
                Hf[off] = hn;
                Hbf[off] = (__bf16)hn;
            }
        }
    }
}

// ---------------- transpose small weight (256,512) -> (512,256) ----------------
__global__ __launch_bounds__(256) void transpose_w(const float* __restrict__ w, float* __restrict__ wt) {
    int idx = blockIdx.x * 256 + threadIdx.x;   // 131072
    int k = idx >> 8, n = idx & 255;
    wt[idx] = w[n * 512 + k];
}

// ---------------- fused scorer MLP (fp32) ----------------
__global__ __launch_bounds__(256) void score_mlp(
    const float* __restrict__ H, const float* __restrict__ WT,
    const float* __restrict__ bias1, const float* __restrict__ wsm,
    const float* __restrict__ bias2, float* __restrict__ outv, int inner, int off) {
    __shared__ float xs[16][36];
    __shared__ float wsb[16][260];
    __shared__ float red[32][33];
    int t = threadIdx.x;
    int mb = blockIdx.x * 32;
    int rr = t >> 3;
    int kq = (t & 7) * 2;
    int mrow = mb + rr;
    int src = (mrow / inner) * 13 + off + (mrow % inner);
    int tn = t & 31, tm = t >> 5;
    int n0 = tn * 8, m0 = tm * 4;
    int nw4 = (t & 63) * 4;
    int kr = t >> 6;
    float acc[4][8] = {};
    for (int kc = 0; kc < 512; kc += 16) {
        float2 xv = *(const float2*)&H[(size_t)src * HDIM + kc + kq];
        float4 wv[4];
#pragma unroll
        for (int u = 0; u < 4; ++u) wv[u] = *(const float4*)&WT[(kc + kr * 4 + u) * 256 + nw4];
        __syncthreads();
        xs[kq][rr] = xv.x;
        xs[kq + 1][rr] = xv.y;
#pragma unroll
        for (int u = 0; u < 4; ++u) *(float4*)&wsb[kr * 4 + u][nw4] = wv[u];
        __syncthreads();
#pragma unroll
        for (int kk = 0; kk < 16; ++kk) {
            float4 x4 = *(float4*)&xs[kk][m0];
            float4 w0 = *(float4*)&wsb[kk][n0];
            float4 w1v = *(float4*)&wsb[kk][n0 + 4];
            float xx[4] = {x4.x, x4.y, x4.z, x4.w};
            float wa[8] = {w0.x, w0.y, w0.z, w0.w, w1v.x, w1v.y, w1v.z, w1v.w};
#pragma unroll
            for (int i = 0; i < 4; ++i)
#pragma unroll
                for (int j = 0; j < 8; ++j) acc[i][j] = fmaf(xx[i], wa[j], acc[i][j]);
        }
    }
    float part[4];
#pragma unroll
    for (int i = 0; i < 4; ++i) {
        float s = 0.0f;
#pragma unroll
        for (int j = 0; j < 8; ++j) {
            int n = n0 + j;
            float v = acc[i][j] + bias1[n];
            v = v > 0.0f ? v : 0.0f;
            s = fmaf(v, wsm[n], s);
        }
        part[i] = s;
    }
    __syncthreads();
#pragma unroll
    for (int i = 0; i < 4; ++i) red[m0 + i][tn] = part[i];
    __syncthreads();
    if (t < 32) {
        float s = 0.0f;
#pragma unroll
        for (int q = 0; q < 32; ++q) s += red[t][q];
        s += bias2[0];
        outv[mb + t] = s > 0.0f ? s : 0.0f;
    }
}

// ---------------- final: softmax over 8 ctx nodes, weighted sum, -L2 distance ----------------
__global__ __launch_bounds__(256) void final_kernel(const float* __restrict__ H,
                                                    const float* __restrict__ UAv,
                                                    const float* __restrict__ UBv,
                                                    float* __restrict__ outv) {
    int b = blockIdx.x;
    int t = threadIdx.x;
    __shared__ float ctx[8][512];
    __shared__ float uas[8], ubs[5];
    __shared__ float red[4];
#pragma unroll
    for (int q = 0; q < 16; ++q) {
        int idx = q * 256 + t;
        int j = idx >> 9, c = idx & 511;
        ctx[j][c] = H[(size_t)(b * 13 + j) * HDIM + c];
    }
    if (t < 8) uas[t] = UAv[b * 8 + t];
    if (t < 5) ubs[t] = UBv[b * 5 + t];
    __syncthreads();
    int c0 = t, c1 = t + 256;
    int wid = t >> 6, lane = t & 63;
    for (int s = 0; s < 5; ++s) {
        float wn[8];
        float sum = 0.0f;
#pragma unroll
        for (int j = 0; j < 8; ++j) {
            wn[j] = __expf(tanhf(uas[j] + ubs[s]));
            sum += wn[j];
        }
        float inv = 1.0f / sum;
        float av0 = 0.0f, av1 = 0.0f;
#pragma unroll
        for (int j = 0; j < 8; ++j) {
            av0 = fmaf(wn[j], ctx[j][c0], av0);
            av1 = fmaf(wn[j], ctx[j][c1], av1);
        }
        av0 *= inv;
        av1 *= inv;
        float d0 = av0 - H[(size_t)(b * 13 + 8 + s) * HDIM + c0];
        float d1 = av1 - H[(size_t)(b * 13 + 8 + s) * HDIM + c1];
        float v = d0 * d0 + d1 * d1;
#pragma unroll
        for (int o = 32; o > 0; o >>= 1) v += __shfl_down(v, o);
        if (lane == 0) red[wid] = v;
        __syncthreads();
        if (t == 0) outv[b * 5 + s] = -sqrtf(red[0] + red[1] + red[2] + red[3]);
        __syncthreads();
    }
}

extern "C" void kernel_launch(void* const* d_in, const int* in_sizes, int n_in,
                              void* d_out, int out_size, void* d_ws, size_t ws_size,
                              hipStream_t stream) {
    const float* Ain  = (const float*)d_in[0];
    const int*   ids  = (const int*)d_in[1];
    const float* emb  = (const float*)d_in[2];
    const float* b_ah = (const float*)d_in[3];
    const float* w_z  = (const float*)d_in[4];
    const float* b_wz = (const float*)d_in[5];
    const float* u_z  = (const float*)d_in[6];
    const float* b_uz = (const float*)d_in[7];
    const float* w_r  = (const float*)d_in[8];
    const float* b_wr = (const float*)d_in[9];
    const float* u_r  = (const float*)d_in[10];
    const float* b_ur = (const float*)d_in[11];
    const float* w_   = (const float*)d_in[12];
    const float* b_w  = (const float*)d_in[13];
    const float* u_u  = (const float*)d_in[14];
    const float* b_u  = (const float*)d_in[15];
    const float* w1   = (const float*)d_in[16];
    const float* b1   = (const float*)d_in[17];
    const float* w12  = (const float*)d_in[18];
    const float* b12  = (const float*)d_in[19];
    const float* w2   = (const float*)d_in[20];
    const float* b2   = (const float*)d_in[21];
    const float* w22  = (const float*)d_in[22];
    const float* b22  = (const float*)d_in[23];
    float* out = (float*)d_out;

    // ---- chunk size: rows=13C divisible by 128 -> C multiple of 128 ----
    // per-elem: Hf4 + Zf4 + Hbf2 + Abf2 + RHbf2 = 14B
    int C = 128;
    {
        const int cands[6] = {4096, 2048, 1024, 512, 256, 128};
        for (int ci = 0; ci < 6; ++ci) {
            int cc = cands[ci];
            size_t rows = (size_t)13 * cc;
            size_t need = rows * 512 * 14
                        + 6 * (size_t)262144 * 2
                        + 2 * (size_t)131072 * 4
                        + (size_t)13 * cc * 4
                        + (4u << 20);
            if (need <= ws_size) { C = cc; break; }
        }
    }
    const int rows = 13 * C;

    char* base = (char*)d_ws;
    __bf16* Wzb = (__bf16*)base; base += 262144 * 2;
    __bf16* Uzb = (__bf16*)base; base += 262144 * 2;
    __bf16* Wrb = (__bf16*)base; base += 262144 * 2;
    __bf16* Urb = (__bf16*)base; base += 262144 * 2;
    __bf16* Wb  = (__bf16*)base; base += 262144 * 2;
    __bf16* Ub  = (__bf16*)base; base += 262144 * 2;
    float* W1T = (float*)base; base += 131072 * 4;
    float* W2T = (float*)base; base += 131072 * 4;
    float* UA  = (float*)base; base += (size_t)8 * C * 4;
    float* UB  = (float*)base; base += (size_t)5 * C * 4;
    float* Hf  = (float*)base; base += (size_t)rows * 512 * 4;
    float* Zf  = (float*)base; base += (size_t)rows * 512 * 4;
    __bf16* Hbf  = (__bf16*)base; base += (size_t)rows * 512 * 2;
    __bf16* Abf  = (__bf16*)base; base += (size_t)rows * 512 * 2;
    __bf16* RHbf = (__bf16*)base; base += (size_t)rows * 512 * 2;

    f2bf<<<128, 256, 0, stream>>>(w_z, Wzb, 262144);
    f2bf<<<128, 256, 0, stream>>>(u_z, Uzb, 262144);
    f2bf<<<128, 256, 0, stream>>>(w_r, Wrb, 262144);
    f2bf<<<128, 256, 0, stream>>>(u_r, Urb, 262144);
    f2bf<<<128, 256, 0, stream>>>(w_, Wb, 262144);
    f2bf<<<128, 256, 0, stream>>>(u_u, Ub, 262144);
    transpose_w<<<512, 256, 0, stream>>>(w1, W1T);
    transpose_w<<<512, 256, 0, stream>>>(w2, W2T);

    dim3 ggrid(rows / 128, 4);
    for (int g0 = 0; g0 < 4096; g0 += C) {
        gather_kernel<<<rows, 512, 0, stream>>>(ids + (size_t)g0 * 52, emb, Hf, Hbf);
        for (int it = 0; it < 2; ++it) {
            a_kernel<<<C, 512, 0, stream>>>(Ain + (size_t)g0 * 169, Hbf, b_ah, Abf);
            zr_fused<<<ggrid, 512, 0, stream>>>(Abf, Hbf, Wzb, Uzb, Wrb, Urb,
                                                b_wz, b_uz, b_wr, b_ur, Zf, RHbf);
            c_fused<<<ggrid, 256, 0, stream>>>(Abf, RHbf, Wb, Ub, b_w, b_u, Zf, Hf, Hbf);
        }
        score_mlp<<<C * 8 / 32, 256, 0, stream>>>(Hf, W1T, b1, w12, b12, UA, 8, 0);
        score_mlp<<<C * 5 / 32, 256, 0, stream>>>(Hf, W2T, b2, w22, b22, UB, 5, 8);
        final_kernel<<<C, 256, 0, stream>>>(Hf, UA, UB, out + (size_t)g0 * 5);
    }
}

// Round 5
// 1016.220 us; speedup vs baseline: 4.6612x; 1.2446x over previous
//
#include <hip/hip_runtime.h>
#include <hip/hip_bf16.h>
#include <math.h>

#define HDIM 512

typedef __attribute__((ext_vector_type(8))) __bf16 bf16x8;
typedef __attribute__((ext_vector_type(2))) __bf16 bf16x2;
typedef __attribute__((ext_vector_type(4))) float f32x4;

#define GLOAD16(src, dst) __builtin_amdgcn_global_load_lds( \
    (const __attribute__((address_space(1))) void*)(src),   \
    (__attribute__((address_space(3))) void*)(dst), 16, 0, 0)

__device__ __forceinline__ float sigmoidf_(float x) { return 1.0f / (1.0f + __expf(-x)); }

// ---------------- fp32 -> bf16 copy (weights) ----------------
__global__ __launch_bounds__(256) void f2bf(const float* __restrict__ s, __bf16* __restrict__ d, int n) {
    int i = blockIdx.x * 256 + threadIdx.x;
    int stride = gridDim.x * 256;
    for (; i < n; i += stride) d[i] = (__bf16)s[i];
}

// ---------------- gather: h0 fp32 + bf16 ----------------
__global__ __launch_bounds__(512) void gather_kernel(const int* __restrict__ ids,
                                                     const float* __restrict__ emb,
                                                     float* __restrict__ Hf,
                                                     __bf16* __restrict__ Hbf) {
    int bj = blockIdx.x;            // chunk-local b*13 + j
    int b = bj / 13, j = bj - b * 13;
    int c = threadIdx.x;
    int i = c >> 7, e = c & 127;
    int id = ids[b * 52 + i * 13 + j];
    float v = emb[(size_t)id * 128 + e];
    Hf[(size_t)bj * HDIM + c] = v;
    Hbf[(size_t)bj * HDIM + c] = (__bf16)v;
}

// ---------------- a = At @ h + b_ah (per-graph 13x13 bmm), bf16 h, 2 channels/thread ----------------
__global__ __launch_bounds__(256) void a_kernel(const float* __restrict__ Ain,
                                                const __bf16* __restrict__ Hbf,
                                                const float* __restrict__ bah,
                                                __bf16* __restrict__ Abf) {
    int b = blockIdx.x;
    int c2 = threadIdx.x;           // channel pair 0..255
    __shared__ float As[169];
    if (c2 < 169) As[c2] = Ain[b * 169 + c2];
    float h0[13], h1[13];
#pragma unroll
    for (int j = 0; j < 13; ++j) {
        bf16x2 hv = *(const bf16x2*)&Hbf[(size_t)(b * 13 + j) * HDIM + c2 * 2];
        h0[j] = (float)hv[0];
        h1[j] = (float)hv[1];
    }
    __syncthreads();
    float bb0 = bah[c2 * 2], bb1 = bah[c2 * 2 + 1];
#pragma unroll
    for (int i = 0; i < 13; ++i) {
        float acc0 = bb0, acc1 = bb1;
#pragma unroll
        for (int j = 0; j < 13; ++j) {
            float a = As[j * 13 + i];
            acc0 = fmaf(a, h0[j], acc0);
            acc1 = fmaf(a, h1[j], acc1);
        }
        bf16x2 o;
        o[0] = (__bf16)acc0;
        o[1] = (__bf16)acc1;
        *(bf16x2*)&Abf[(size_t)(b * 13 + i) * HDIM + c2 * 2] = o;
    }
}

// ================= fused z+r GEMM, double-buffered counted-vmcnt pipeline =================
// 512 threads = 8 waves. role=(w&1): 0->z, 1->r. wq=w>>1 -> 2x2 quadrant.
// Tile 128x128, BK=32, K = 512(a-side)+512(h-side) = 32 steps.
__global__ __launch_bounds__(512) void zr_fused(
    const __bf16* __restrict__ Abf, const __bf16* __restrict__ Hbf,
    const __bf16* __restrict__ Wz, const __bf16* __restrict__ Uz,
    const __bf16* __restrict__ Wr, const __bf16* __restrict__ Ur,
    const float* __restrict__ bwz, const float* __restrict__ buz,
    const float* __restrict__ bwr, const float* __restrict__ bur,
    float* __restrict__ Zf, __bf16* __restrict__ RHbf) {
    __shared__ __bf16 lA[2][4096];     // [buf][128x32]
    __shared__ __bf16 lB[2][8192];     // [buf][role*4096 + 128x32]
    int t = threadIdx.x;
    int w = t >> 6, lane = t & 63;
    int role = w & 1;
    int wq = w >> 1;
    int wr2 = wq >> 1, wc2 = wq & 1;
    int m_base = blockIdx.x * 128;
    int n_base = blockIdx.y * 128;

    f32x4 acc[4][4];
#pragma unroll
    for (int i = 0; i < 4; ++i)
#pragma unroll
        for (int j = 0; j < 4; ++j)
#pragma unroll
            for (int q = 0; q < 4; ++q) acc[i][j][q] = 0.0f;

    int srow = t >> 2;
    int scol = ((t & 3) ^ ((t >> 3) & 3)) << 3;   // pre-swizzled source slot (involution)
    size_t aoff = (size_t)(m_base + srow) * HDIM + scol;
    size_t boff = (size_t)(n_base + srow) * HDIM + scol;
    int frow = lane & 15, kg = lane >> 4;
    int rsl = kg ^ ((frow >> 1) & 3);

    auto stage = [&](int step, int buf) {
        int seg = step >> 4;
        int kc = (step & 15) << 5;
        const __bf16* Xp = seg ? Hbf : Abf;
        const __bf16* B0 = seg ? Uz : Wz;
        const __bf16* B1 = seg ? Ur : Wr;
        GLOAD16(Xp + aoff + kc, &lA[buf][w * 512]);
        GLOAD16(B0 + boff + kc, &lB[buf][w * 512]);
        GLOAD16(B1 + boff + kc, &lB[buf][4096 + w * 512]);
    };

    stage(0, 0);
    int cur = 0;
    for (int step = 0; step < 32; ++step) {
        if (step < 31) {
            stage(step + 1, cur ^ 1);
            asm volatile("s_waitcnt vmcnt(3)" ::: "memory");
        } else {
            asm volatile("s_waitcnt vmcnt(0)" ::: "memory");
        }
        __builtin_amdgcn_s_barrier();
        bf16x8 af[4], bfr[4];
#pragma unroll
        for (int i = 0; i < 4; ++i) {
            af[i] = *(const bf16x8*)&lA[cur][(wr2 * 64 + i * 16 + frow) * 32 + rsl * 8];
            bfr[i] = *(const bf16x8*)&lB[cur][role * 4096 + (wc2 * 64 + i * 16 + frow) * 32 + rsl * 8];
        }
#pragma unroll
        for (int i = 0; i < 4; ++i)
#pragma unroll
            for (int j = 0; j < 4; ++j)
                acc[i][j] = __builtin_amdgcn_mfma_f32_16x16x32_bf16(af[i], bfr[j], acc[i][j], 0, 0, 0);
        __builtin_amdgcn_s_barrier();
        cur ^= 1;
    }

    int frow4 = (lane >> 4) * 4;
    int fcol = lane & 15;
#pragma unroll
    for (int i = 0; i < 4; ++i) {
#pragma unroll
        for (int j = 0; j < 4; ++j) {
            int col = n_base + wc2 * 64 + j * 16 + fcol;
            float bias = role ? (bwr[col] + bur[col]) : (bwz[col] + buz[col]);
            int rbase = m_base + wr2 * 64 + i * 16 + frow4;
#pragma unroll
            for (int q = 0; q < 4; ++q) {
                size_t off = (size_t)(rbase + q) * HDIM + col;
                float v = sigmoidf_(acc[i][j][q] + bias);
                if (role) {
                    RHbf[off] = (__bf16)(v * (float)Hbf[off]);
                } else {
                    Zf[off] = v;
                }
            }
        }
    }
}

// ================= c GEMM + gated update, double-buffered pipeline =================
// 256 threads = 4 waves (2x2), tile 128x128, BK=32, K=1024 = 32 steps.
__global__ __launch_bounds__(256) void c_fused(
    const __bf16* __restrict__ Abf, const __bf16* __restrict__ RHbf,
    const __bf16* __restrict__ W, const __bf16* __restrict__ U,
    const float* __restrict__ bw, const float* __restrict__ bu,
    const float* __restrict__ Zf, float* __restrict__ Hf, __bf16* __restrict__ Hbf) {
    __shared__ __bf16 lA[2][4096];
    __shared__ __bf16 lB[2][4096];
    int t = threadIdx.x;
    int w = t >> 6, lane = t & 63;
    int wr = w >> 1, wc = w & 1;
    int m_base = blockIdx.x * 128;
    int n_base = blockIdx.y * 128;

    f32x4 acc[4][4];
#pragma unroll
    for (int i = 0; i < 4; ++i)
#pragma unroll
        for (int j = 0; j < 4; ++j)
#pragma unroll
            for (int q = 0; q < 4; ++q) acc[i][j][q] = 0.0f;

    int srow = t >> 2;                               // 0..63, + u*64
    int scol = ((t & 3) ^ ((t >> 3) & 3)) << 3;
    size_t aoff = (size_t)(m_base + srow) * HDIM + scol;
    size_t boff = (size_t)(n_base + srow) * HDIM + scol;
    int frow = lane & 15, kg = lane >> 4;
    int rsl = kg ^ ((frow >> 1) & 3);

    auto stage = [&](int step, int buf) {
        int seg = step >> 4;
        int kc = (step & 15) << 5;
        const __bf16* Xp = seg ? RHbf : Abf;
        const __bf16* Wp = seg ? U : W;
#pragma unroll
        for (int u = 0; u < 2; ++u) {
            GLOAD16(Xp + aoff + (size_t)u * 64 * HDIM + kc, &lA[buf][u * 2048 + w * 512]);
            GLOAD16(Wp + boff + (size_t)u * 64 * HDIM + kc, &lB[buf][u * 2048 + w * 512]);
        }
    };

    stage(0, 0);
    int cur = 0;
    for (int step = 0; step < 32; ++step) {
        if (step < 31) {
            stage(step + 1, cur ^ 1);
            asm volatile("s_waitcnt vmcnt(4)" ::: "memory");
        } else {
            asm volatile("s_waitcnt vmcnt(0)" ::: "memory");
        }
        __builtin_amdgcn_s_barrier();
        bf16x8 af[4], bfr[4];
#pragma unroll
        for (int i = 0; i < 4; ++i) {
            af[i] = *(const bf16x8*)&lA[cur][(wr * 64 + i * 16 + frow) * 32 + rsl * 8];
            bfr[i] = *(const bf16x8*)&lB[cur][(wc * 64 + i * 16 + frow) * 32 + rsl * 8];
        }
#pragma unroll
        for (int i = 0; i < 4; ++i)
#pragma unroll
            for (int j = 0; j < 4; ++j)
                acc[i][j] = __builtin_amdgcn_mfma_f32_16x16x32_bf16(af[i], bfr[j], acc[i][j], 0, 0, 0);
        __builtin_amdgcn_s_barrier();
        cur ^= 1;
    }

    int frow4 = (lane >> 4) * 4;
    int fcol = lane & 15;
#pragma unroll
    for (int i = 0; i < 4; ++i) {
#pragma unroll
        for (int j = 0; j < 4; ++j) {
            int col = n_base + wc * 64 + j * 16 + fcol;
            float bias = bw[col] + bu[col];
            int rbase = m_base + wr * 64 + i * 16 + frow4;
#pragma unroll
            for (int q = 0; q < 4; ++q) {
                size_t off = (size_t)(rbase + q) * HDIM + col;
                float v = acc[i][j][q] + bias;
                float x = v > 15.0f ? 15.0f : (v < -15.0f ? -15.0f : v);
                float e = __expf(2.0f * x);
                float cv = (e - 1.0f) / (e + 1.0f);
                float h = Hf[off], z = Zf[off];
                float hn = (1.0f - z) * h + z * cv;
                Hf[off] = hn;
                Hbf[off] = (__bf16)hn;
            }
        }
    }
}

// ================= merged scorer: bf16 MFMA GEMM (Mx256, K=512) + fused relu/dot/relu =================
// out[m] = relu( b2 + sum_n wsm[n] * relu( sum_k X[m,k]*W[n,k] + b1[n] ) )
// X row m -> h row (m/inner)*13 + off + (m%inner).
// blocks [0, nblkA) -> scorer A (inner=8, off=0); rest -> scorer B (inner=5, off=8).
// 512 threads = 8 waves (2 wr x 4 wc), tile 128(M) x 256(N), BK=32, 16 steps.
__global__ __launch_bounds__(512) void score_mfma(
    const __bf16* __restrict__ Hbf,
    const __bf16* __restrict__ W1b, const __bf16* __restrict__ W2b,
    const float* __restrict__ b1A, const float* __restrict__ b1B,
    const float* __restrict__ wsA, const float* __restrict__ wsB,
    const float* __restrict__ b2A, const float* __restrict__ b2B,
    float* __restrict__ UA, float* __restrict__ UB, int nblkA) {
    __shared__ __bf16 lA[2][4096];     // 128x32
    __shared__ __bf16 lB[2][8192];     // 256x32
    __shared__ float red[128][5];
    int t = threadIdx.x;
    int w = t >> 6, lane = t & 63;
    int wr = w >> 2, wc = w & 3;

    const __bf16* Wb;
    const float* bias1;
    const float* wsm;
    const float* bias2;
    float* outv;
    int inner, off, m_base;
    if ((int)blockIdx.x < nblkA) {
        Wb = W1b; bias1 = b1A; wsm = wsA; bias2 = b2A; outv = UA;
        inner = 8; off = 0; m_base = blockIdx.x * 128;
    } else {
        Wb = W2b; bias1 = b1B; wsm = wsB; bias2 = b2B; outv = UB;
        inner = 5; off = 8; m_base = (blockIdx.x - nblkA) * 128;
    }

    f32x4 acc[4][4];
#pragma unroll
    for (int i = 0; i < 4; ++i)
#pragma unroll
        for (int j = 0; j < 4; ++j)
#pragma unroll
            for (int q = 0; q < 4; ++q) acc[i][j][q] = 0.0f;

    int srow = t >> 2;
    int scol = ((t & 3) ^ ((t >> 3) & 3)) << 3;
    int mrow = m_base + srow;
    int hrow = (mrow / inner) * 13 + off + (mrow % inner);
    size_t aoff = (size_t)hrow * HDIM + scol;
    size_t boff = (size_t)srow * HDIM + scol;
    int frow = lane & 15, kg = lane >> 4;
    int rsl = kg ^ ((frow >> 1) & 3);

    auto stage = [&](int step, int buf) {
        int kc = step << 5;
        GLOAD16(Hbf + aoff + kc, &lA[buf][w * 512]);
        GLOAD16(Wb + boff + kc, &lB[buf][w * 512]);
        GLOAD16(Wb + boff + (size_t)128 * HDIM + kc, &lB[buf][4096 + w * 512]);
    };

    stage(0, 0);
    int cur = 0;
    for (int step = 0; step < 16; ++step) {
        if (step < 15) {
            stage(step + 1, cur ^ 1);
            asm volatile("s_waitcnt vmcnt(3)" ::: "memory");
        } else {
            asm volatile("s_waitcnt vmcnt(0)" ::: "memory");
        }
        __builtin_amdgcn_s_barrier();
        bf16x8 af[4], bfr[4];
#pragma unroll
        for (int i = 0; i < 4; ++i) {
            af[i] = *(const bf16x8*)&lA[cur][(wr * 64 + i * 16 + frow) * 32 + rsl * 8];
            bfr[i] = *(const bf16x8*)&lB[cur][(wc * 64 + i * 16 + frow) * 32 + rsl * 8];
        }
#pragma unroll
        for (int i = 0; i < 4; ++i)
#pragma unroll
            for (int j = 0; j < 4; ++j)
                acc[i][j] = __builtin_amdgcn_mfma_f32_16x16x32_bf16(af[i], bfr[j], acc[i][j], 0, 0, 0);
        __builtin_amdgcn_s_barrier();
        cur ^= 1;
    }

    // epilogue: relu + dot with wsm over this wave's 64 cols, butterfly over 16 col-lanes
    int frow4 = (lane >> 4) * 4;
    int fcol = lane & 15;
#pragma unroll
    for (int i = 0; i < 4; ++i) {
#pragma unroll
        for (int q = 0; q < 4; ++q) {
            float s = 0.0f;
#pragma unroll
            for (int j = 0; j < 4; ++j) {
                int col = wc * 64 + j * 16 + fcol;
                float v = acc[i][j][q] + bias1[col];
                v = v > 0.0f ? v : 0.0f;
                s = fmaf(v, wsm[col], s);
            }
            s += __shfl_xor(s, 1);
            s += __shfl_xor(s, 2);
            s += __shfl_xor(s, 4);
            s += __shfl_xor(s, 8);
            if (fcol == 0) red[wr * 64 + i * 16 + frow4 + q][wc] = s;
        }
    }
    __syncthreads();
    if (t < 128) {
        float s = red[t][0] + red[t][1] + red[t][2] + red[t][3] + bias2[0];
        outv[m_base + t] = s > 0.0f ? s : 0.0f;
    }
}

// ---------------- final: softmax over 8 ctx nodes, weighted sum, -L2 distance ----------------
__global__ __launch_bounds__(256) void final_kernel(const float* __restrict__ H,
                                                    const float* __restrict__ UAv,
                                                    const float* __restrict__ UBv,
                                                    float* __restrict__ outv) {
    int b = blockIdx.x;
    int t = threadIdx.x;
    __shared__ float ctx[8][512];
    __shared__ float uas[8], ubs[5];
    __shared__ float red[4];
#pragma unroll
    for (int q = 0; q < 16; ++q) {
        int idx = q * 256 + t;
        int j = idx >> 9, c = idx & 511;
        ctx[j][c] = H[(size_t)(b * 13 + j) * HDIM + c];
    }
    if (t < 8) uas[t] = UAv[b * 8 + t];
    if (t < 5) ubs[t] = UBv[b * 5 + t];
    __syncthreads();
    int c0 = t, c1 = t + 256;
    int wid = t >> 6, lane = t & 63;
    for (int s = 0; s < 5; ++s) {
        float wn[8];
        float sum = 0.0f;
#pragma unroll
        for (int j = 0; j < 8; ++j) {
            wn[j] = __expf(tanhf(uas[j] + ubs[s]));
            sum += wn[j];
        }
        float inv = 1.0f / sum;
        float av0 = 0.0f, av1 = 0.0f;
#pragma unroll
        for (int j = 0; j < 8; ++j) {
            av0 = fmaf(wn[j], ctx[j][c0], av0);
            av1 = fmaf(wn[j], ctx[j][c1], av1);
        }
        av0 *= inv;
        av1 *= inv;
        float d0 = av0 - H[(size_t)(b * 13 + 8 + s) * HDIM + c0];
        float d1 = av1 - H[(size_t)(b * 13 + 8 + s) * HDIM + c1];
        float v = d0 * d0 + d1 * d1;
#pragma unroll
        for (int o = 32; o > 0; o >>= 1) v += __shfl_down(v, o);
        if (lane == 0) red[wid] = v;
        __syncthreads();
        if (t == 0) outv[b * 5 + s] = -sqrtf(red[0] + red[1] + red[2] + red[3]);
        __syncthreads();
    }
}

extern "C" void kernel_launch(void* const* d_in, const int* in_sizes, int n_in,
                              void* d_out, int out_size, void* d_ws, size_t ws_size,
                              hipStream_t stream) {
    const float* Ain  = (const float*)d_in[0];
    const int*   ids  = (const int*)d_in[1];
    const float* emb  = (const float*)d_in[2];
    const float* b_ah = (const float*)d_in[3];
    const float* w_z  = (const float*)d_in[4];
    const float* b_wz = (const float*)d_in[5];
    const float* u_z  = (const float*)d_in[6];
    const float* b_uz = (const float*)d_in[7];
    const float* w_r  = (const float*)d_in[8];
    const float* b_wr = (const float*)d_in[9];
    const float* u_r  = (const float*)d_in[10];
    const float* b_ur = (const float*)d_in[11];
    const float* w_   = (const float*)d_in[12];
    const float* b_w  = (const float*)d_in[13];
    const float* u_u  = (const float*)d_in[14];
    const float* b_u  = (const float*)d_in[15];
    const float* w1   = (const float*)d_in[16];
    const float* b1   = (const float*)d_in[17];
    const float* w12  = (const float*)d_in[18];
    const float* b12  = (const float*)d_in[19];
    const float* w2   = (const float*)d_in[20];
    const float* b2   = (const float*)d_in[21];
    const float* w22  = (const float*)d_in[22];
    const float* b22  = (const float*)d_in[23];
    float* out = (float*)d_out;

    // ---- chunk size: rows=13C divisible by 128 -> C multiple of 128 ----
    // per-elem: Hf4 + Zf4 + Hbf2 + Abf2 + RHbf2 = 14B
    int C = 128;
    {
        const int cands[6] = {4096, 2048, 1024, 512, 256, 128};
        for (int ci = 0; ci < 6; ++ci) {
            int cc = cands[ci];
            size_t rows = (size_t)13 * cc;
            size_t need = rows * 512 * 14
                        + 6 * (size_t)262144 * 2
                        + 2 * (size_t)131072 * 2
                        + (size_t)13 * cc * 4
                        + (4u << 20);
            if (need <= ws_size) { C = cc; break; }
        }
    }
    const int rows = 13 * C;

    char* base = (char*)d_ws;
    __bf16* Wzb = (__bf16*)base; base += 262144 * 2;
    __bf16* Uzb = (__bf16*)base; base += 262144 * 2;
    __bf16* Wrb = (__bf16*)base; base += 262144 * 2;
    __bf16* Urb = (__bf16*)base; base += 262144 * 2;
    __bf16* Wb  = (__bf16*)base; base += 262144 * 2;
    __bf16* Ub  = (__bf16*)base; base += 262144 * 2;
    __bf16* W1b = (__bf16*)base; base += 131072 * 2;
    __bf16* W2b = (__bf16*)base; base += 131072 * 2;
    float* UA  = (float*)base; base += (size_t)8 * C * 4;
    float* UB  = (float*)base; base += (size_t)5 * C * 4;
    float* Hf  = (float*)base; base += (size_t)rows * 512 * 4;
    float* Zf  = (float*)base; base += (size_t)rows * 512 * 4;
    __bf16* Hbf  = (__bf16*)base; base += (size_t)rows * 512 * 2;
    __bf16* Abf  = (__bf16*)base; base += (size_t)rows * 512 * 2;
    __bf16* RHbf = (__bf16*)base; base += (size_t)rows * 512 * 2;

    f2bf<<<128, 256, 0, stream>>>(w_z, Wzb, 262144);
    f2bf<<<128, 256, 0, stream>>>(u_z, Uzb, 262144);
    f2bf<<<128, 256, 0, stream>>>(w_r, Wrb, 262144);
    f2bf<<<128, 256, 0, stream>>>(u_r, Urb, 262144);
    f2bf<<<128, 256, 0, stream>>>(w_, Wb, 262144);
    f2bf<<<128, 256, 0, stream>>>(u_u, Ub, 262144);
    f2bf<<<64, 256, 0, stream>>>(w1, W1b, 131072);
    f2bf<<<64, 256, 0, stream>>>(w2, W2b, 131072);

    dim3 ggrid(rows / 128, 4);
    int nblkA = 8 * C / 128;
    int nblkB = 5 * C / 128;
    for (int g0 = 0; g0 < 4096; g0 += C) {
        gather_kernel<<<rows, 512, 0, stream>>>(ids + (size_t)g0 * 52, emb, Hf, Hbf);
        for (int it = 0; it < 2; ++it) {
            a_kernel<<<C, 256, 0, stream>>>(Ain + (size_t)g0 * 169, Hbf, b_ah, Abf);
            zr_fused<<<ggrid, 512, 0, stream>>>(Abf, Hbf, Wzb, Uzb, Wrb, Urb,
                                                b_wz, b_uz, b_wr, b_ur, Zf, RHbf);
            c_fused<<<ggrid, 256, 0, stream>>>(Abf, RHbf, Wb, Ub, b_w, b_u, Zf, Hf, Hbf);
        }
        score_mfma<<<nblkA + nblkB, 512, 0, stream>>>(Hbf, W1b, W2b, b1, b2, w12, w22,
                                                      b12, b22, UA, UB, nblkA);
        final_kernel<<<C, 256, 0, stream>>>(Hf, UA, UB, out + (size_t)g0 * 5);
    }
}

// Round 6
// 863.056 us; speedup vs baseline: 5.4884x; 1.1775x over previous
//
#include <hip/hip_runtime.h>
#include <hip/hip_bf16.h>
#include <math.h>

#define HDIM 512

typedef __attribute__((ext_vector_type(8))) __bf16 bf16x8;
typedef __attribute__((ext_vector_type(2))) __bf16 bf16x2;
typedef __attribute__((ext_vector_type(4))) float f32x4;

#define GLOAD16(src, dst) __builtin_amdgcn_global_load_lds( \
    (const __attribute__((address_space(1))) void*)(src),   \
    (__attribute__((address_space(3))) void*)(dst), 16, 0, 0)

__device__ __forceinline__ float sigmoidf_(float x) { return 1.0f / (1.0f + __expf(-x)); }

// ---------------- fp32 -> bf16 copy (weights) ----------------
__global__ __launch_bounds__(256) void f2bf(const float* __restrict__ s, __bf16* __restrict__ d, int n) {
    int i = blockIdx.x * 256 + threadIdx.x;
    int stride = gridDim.x * 256;
    for (; i < n; i += stride) d[i] = (__bf16)s[i];
}

// ---------------- gather: h0 -> bf16 only ----------------
__global__ __launch_bounds__(512) void gather_kernel(const int* __restrict__ ids,
                                                     const float* __restrict__ emb,
                                                     __bf16* __restrict__ Hbf) {
    int bj = blockIdx.x;            // chunk-local b*13 + j
    int b = bj / 13, j = bj - b * 13;
    int c = threadIdx.x;
    int i = c >> 7, e = c & 127;
    int id = ids[b * 52 + i * 13 + j];
    float v = emb[(size_t)id * 128 + e];
    Hbf[(size_t)bj * HDIM + c] = (__bf16)v;
}

// ---------------- a = At @ h + b_ah (per-graph 13x13 bmm), bf16 h, 2 channels/thread ----------------
__global__ __launch_bounds__(256) void a_kernel(const float* __restrict__ Ain,
                                                const __bf16* __restrict__ Hbf,
                                                const float* __restrict__ bah,
                                                __bf16* __restrict__ Abf) {
    int b = blockIdx.x;
    int c2 = threadIdx.x;           // channel pair 0..255
    __shared__ float As[169];
    if (c2 < 169) As[c2] = Ain[b * 169 + c2];
    float h0[13], h1[13];
#pragma unroll
    for (int j = 0; j < 13; ++j) {
        bf16x2 hv = *(const bf16x2*)&Hbf[(size_t)(b * 13 + j) * HDIM + c2 * 2];
        h0[j] = (float)hv[0];
        h1[j] = (float)hv[1];
    }
    __syncthreads();
    float bb0 = bah[c2 * 2], bb1 = bah[c2 * 2 + 1];
#pragma unroll
    for (int i = 0; i < 13; ++i) {
        float acc0 = bb0, acc1 = bb1;
#pragma unroll
        for (int j = 0; j < 13; ++j) {
            float a = As[j * 13 + i];
            acc0 = fmaf(a, h0[j], acc0);
            acc1 = fmaf(a, h1[j], acc1);
        }
        bf16x2 o;
        o[0] = (__bf16)acc0;
        o[1] = (__bf16)acc1;
        *(bf16x2*)&Abf[(size_t)(b * 13 + i) * HDIM + c2 * 2] = o;
    }
}

// ================= fused z+r GEMM, double-buffered counted-vmcnt pipeline =================
// 512 threads = 8 waves. role=(w&1): 0->z, 1->r. wq=w>>1 -> 2x2 quadrant.
// Tile 128x128, BK=32, K = 512(a-side)+512(h-side) = 32 steps.
// z -> Zbf (bf16); rh -> RHbf (bf16)
__global__ __launch_bounds__(512) void zr_fused(
    const __bf16* __restrict__ Abf, const __bf16* __restrict__ Hbf,
    const __bf16* __restrict__ Wz, const __bf16* __restrict__ Uz,
    const __bf16* __restrict__ Wr, const __bf16* __restrict__ Ur,
    const float* __restrict__ bwz, const float* __restrict__ buz,
    const float* __restrict__ bwr, const float* __restrict__ bur,
    __bf16* __restrict__ Zbf, __bf16* __restrict__ RHbf) {
    __shared__ __bf16 lA[2][4096];     // [buf][128x32]
    __shared__ __bf16 lB[2][8192];     // [buf][role*4096 + 128x32]
    int t = threadIdx.x;
    int w = t >> 6, lane = t & 63;
    int role = w & 1;
    int wq = w >> 1;
    int wr2 = wq >> 1, wc2 = wq & 1;
    int m_base = blockIdx.x * 128;
    int n_base = blockIdx.y * 128;

    f32x4 acc[4][4];
#pragma unroll
    for (int i = 0; i < 4; ++i)
#pragma unroll
        for (int j = 0; j < 4; ++j)
#pragma unroll
            for (int q = 0; q < 4; ++q) acc[i][j][q] = 0.0f;

    int srow = t >> 2;
    int scol = ((t & 3) ^ ((t >> 3) & 3)) << 3;   // pre-swizzled source slot (involution)
    size_t aoff = (size_t)(m_base + srow) * HDIM + scol;
    size_t boff = (size_t)(n_base + srow) * HDIM + scol;
    int frow = lane & 15, kg = lane >> 4;
    int rsl = kg ^ ((frow >> 1) & 3);

    auto stage = [&](int step, int buf) {
        int seg = step >> 4;
        int kc = (step & 15) << 5;
        const __bf16* Xp = seg ? Hbf : Abf;
        const __bf16* B0 = seg ? Uz : Wz;
        const __bf16* B1 = seg ? Ur : Wr;
        GLOAD16(Xp + aoff + kc, &lA[buf][w * 512]);
        GLOAD16(B0 + boff + kc, &lB[buf][w * 512]);
        GLOAD16(B1 + boff + kc, &lB[buf][4096 + w * 512]);
    };

    stage(0, 0);
    int cur = 0;
    for (int step = 0; step < 32; ++step) {
        if (step < 31) {
            stage(step + 1, cur ^ 1);
            asm volatile("s_waitcnt vmcnt(3)" ::: "memory");
        } else {
            asm volatile("s_waitcnt vmcnt(0)" ::: "memory");
        }
        __builtin_amdgcn_s_barrier();
        bf16x8 af[4], bfr[4];
#pragma unroll
        for (int i = 0; i < 4; ++i) {
            af[i] = *(const bf16x8*)&lA[cur][(wr2 * 64 + i * 16 + frow) * 32 + rsl * 8];
            bfr[i] = *(const bf16x8*)&lB[cur][role * 4096 + (wc2 * 64 + i * 16 + frow) * 32 + rsl * 8];
        }
        __builtin_amdgcn_s_setprio(1);
#pragma unroll
        for (int i = 0; i < 4; ++i)
#pragma unroll
            for (int j = 0; j < 4; ++j)
                acc[i][j] = __builtin_amdgcn_mfma_f32_16x16x32_bf16(af[i], bfr[j], acc[i][j], 0, 0, 0);
        __builtin_amdgcn_s_setprio(0);
        __builtin_amdgcn_s_barrier();
        cur ^= 1;
    }

    int frow4 = (lane >> 4) * 4;
    int fcol = lane & 15;
#pragma unroll
    for (int i = 0; i < 4; ++i) {
#pragma unroll
        for (int j = 0; j < 4; ++j) {
            int col = n_base + wc2 * 64 + j * 16 + fcol;
            float bias = role ? (bwr[col] + bur[col]) : (bwz[col] + buz[col]);
            int rbase = m_base + wr2 * 64 + i * 16 + frow4;
#pragma unroll
            for (int q = 0; q < 4; ++q) {
                size_t off = (size_t)(rbase + q) * HDIM + col;
                float v = sigmoidf_(acc[i][j][q] + bias);
                if (role) {
                    RHbf[off] = (__bf16)(v * (float)Hbf[off]);
                } else {
                    Zbf[off] = (__bf16)v;
                }
            }
        }
    }
}

// ================= c GEMM + gated update, 8 waves, double-buffered pipeline =================
// 512 threads = 8 waves (2 wr x 4 wc), tile 128x128, wave-tile 64x32, BK=32, K=1024 = 32 steps.
// c = tanh(a@w^T + rh@u^T + b); hn = (1-z)h_bf + z*c -> Hbf (always), Hf (last iter only)
__global__ __launch_bounds__(512) void c_fused(
    const __bf16* __restrict__ Abf, const __bf16* __restrict__ RHbf,
    const __bf16* __restrict__ W, const __bf16* __restrict__ U,
    const float* __restrict__ bw, const float* __restrict__ bu,
    const __bf16* __restrict__ Zbf, float* __restrict__ Hf, __bf16* __restrict__ Hbf,
    int lastIter) {
    __shared__ __bf16 lA[2][4096];
    __shared__ __bf16 lB[2][4096];
    int t = threadIdx.x;
    int w = t >> 6, lane = t & 63;
    int wr = w >> 2, wc = w & 3;
    int m_base = blockIdx.x * 128;
    int n_base = blockIdx.y * 128;

    f32x4 acc[4][2];
#pragma unroll
    for (int i = 0; i < 4; ++i)
#pragma unroll
        for (int j = 0; j < 2; ++j)
#pragma unroll
            for (int q = 0; q < 4; ++q) acc[i][j][q] = 0.0f;

    int srow = t >> 2;                               // 0..127
    int scol = ((t & 3) ^ ((t >> 3) & 3)) << 3;
    size_t aoff = (size_t)(m_base + srow) * HDIM + scol;
    size_t boff = (size_t)(n_base + srow) * HDIM + scol;
    int frow = lane & 15, kg = lane >> 4;
    int rsl = kg ^ ((frow >> 1) & 3);

    auto stage = [&](int step, int buf) {
        int seg = step >> 4;
        int kc = (step & 15) << 5;
        const __bf16* Xp = seg ? RHbf : Abf;
        const __bf16* Wp = seg ? U : W;
        GLOAD16(Xp + aoff + kc, &lA[buf][w * 512]);
        GLOAD16(Wp + boff + kc, &lB[buf][w * 512]);
    };

    stage(0, 0);
    int cur = 0;
    for (int step = 0; step < 32; ++step) {
        if (step < 31) {
            stage(step + 1, cur ^ 1);
            asm volatile("s_waitcnt vmcnt(2)" ::: "memory");
        } else {
            asm volatile("s_waitcnt vmcnt(0)" ::: "memory");
        }
        __builtin_amdgcn_s_barrier();
        bf16x8 af[4], bfr[2];
#pragma unroll
        for (int i = 0; i < 4; ++i)
            af[i] = *(const bf16x8*)&lA[cur][(wr * 64 + i * 16 + frow) * 32 + rsl * 8];
#pragma unroll
        for (int j = 0; j < 2; ++j)
            bfr[j] = *(const bf16x8*)&lB[cur][(wc * 32 + j * 16 + frow) * 32 + rsl * 8];
        __builtin_amdgcn_s_setprio(1);
#pragma unroll
        for (int i = 0; i < 4; ++i)
#pragma unroll
            for (int j = 0; j < 2; ++j)
                acc[i][j] = __builtin_amdgcn_mfma_f32_16x16x32_bf16(af[i], bfr[j], acc[i][j], 0, 0, 0);
        __builtin_amdgcn_s_setprio(0);
        __builtin_amdgcn_s_barrier();
        cur ^= 1;
    }

    int frow4 = (lane >> 4) * 4;
    int fcol = lane & 15;
#pragma unroll
    for (int i = 0; i < 4; ++i) {
#pragma unroll
        for (int j = 0; j < 2; ++j) {
            int col = n_base + wc * 32 + j * 16 + fcol;
            float bias = bw[col] + bu[col];
            int rbase = m_base + wr * 64 + i * 16 + frow4;
#pragma unroll
            for (int q = 0; q < 4; ++q) {
                size_t off = (size_t)(rbase + q) * HDIM + col;
                float v = acc[i][j][q] + bias;
                float x = v > 15.0f ? 15.0f : (v < -15.0f ? -15.0f : v);
                float e = __expf(2.0f * x);
                float cv = (e - 1.0f) / (e + 1.0f);
                float h = (float)Hbf[off];
                float z = (float)Zbf[off];
                float hn = (1.0f - z) * h + z * cv;
                Hbf[off] = (__bf16)hn;
                if (lastIter) Hf[off] = hn;
            }
        }
    }
}

// ================= merged scorer: bf16 MFMA GEMM (Mx256, K=512) + fused relu/dot/relu =================
__global__ __launch_bounds__(512) void score_mfma(
    const __bf16* __restrict__ Hbf,
    const __bf16* __restrict__ W1b, const __bf16* __restrict__ W2b,
    const float* __restrict__ b1A, const float* __restrict__ b1B,
    const float* __restrict__ wsA, const float* __restrict__ wsB,
    const float* __restrict__ b2A, const float* __restrict__ b2B,
    float* __restrict__ UA, float* __restrict__ UB, int nblkA) {
    __shared__ __bf16 lA[2][4096];     // 128x32
    __shared__ __bf16 lB[2][8192];     // 256x32
    __shared__ float red[128][5];
    int t = threadIdx.x;
    int w = t >> 6, lane = t & 63;
    int wr = w >> 2, wc = w & 3;

    const __bf16* Wb;
    const float* bias1;
    const float* wsm;
    const float* bias2;
    float* outv;
    int inner, off, m_base;
    if ((int)blockIdx.x < nblkA) {
        Wb = W1b; bias1 = b1A; wsm = wsA; bias2 = b2A; outv = UA;
        inner = 8; off = 0; m_base = blockIdx.x * 128;
    } else {
        Wb = W2b; bias1 = b1B; wsm = wsB; bias2 = b2B; outv = UB;
        inner = 5; off = 8; m_base = (blockIdx.x - nblkA) * 128;
    }

    f32x4 acc[4][4];
#pragma unroll
    for (int i = 0; i < 4; ++i)
#pragma unroll
        for (int j = 0; j < 4; ++j)
#pragma unroll
            for (int q = 0; q < 4; ++q) acc[i][j][q] = 0.0f;

    int srow = t >> 2;
    int scol = ((t & 3) ^ ((t >> 3) & 3)) << 3;
    int mrow = m_base + srow;
    int hrow = (mrow / inner) * 13 + off + (mrow % inner);
    size_t aoff = (size_t)hrow * HDIM + scol;
    size_t boff = (size_t)srow * HDIM + scol;
    int frow = lane & 15, kg = lane >> 4;
    int rsl = kg ^ ((frow >> 1) & 3);

    auto stage = [&](int step, int buf) {
        int kc = step << 5;
        GLOAD16(Hbf + aoff + kc, &lA[buf][w * 512]);
        GLOAD16(Wb + boff + kc, &lB[buf][w * 512]);
        GLOAD16(Wb + boff + (size_t)128 * HDIM + kc, &lB[buf][4096 + w * 512]);
    };

    stage(0, 0);
    int cur = 0;
    for (int step = 0; step < 16; ++step) {
        if (step < 15) {
            stage(step + 1, cur ^ 1);
            asm volatile("s_waitcnt vmcnt(3)" ::: "memory");
        } else {
            asm volatile("s_waitcnt vmcnt(0)" ::: "memory");
        }
        __builtin_amdgcn_s_barrier();
        bf16x8 af[4], bfr[4];
#pragma unroll
        for (int i = 0; i < 4; ++i) {
            af[i] = *(const bf16x8*)&lA[cur][(wr * 64 + i * 16 + frow) * 32 + rsl * 8];
            bfr[i] = *(const bf16x8*)&lB[cur][(wc * 64 + i * 16 + frow) * 32 + rsl * 8];
        }
        __builtin_amdgcn_s_setprio(1);
#pragma unroll
        for (int i = 0; i < 4; ++i)
#pragma unroll
            for (int j = 0; j < 4; ++j)
                acc[i][j] = __builtin_amdgcn_mfma_f32_16x16x32_bf16(af[i], bfr[j], acc[i][j], 0, 0, 0);
        __builtin_amdgcn_s_setprio(0);
        __builtin_amdgcn_s_barrier();
        cur ^= 1;
    }

    // epilogue: relu + dot with wsm over this wave's 64 cols, butterfly over 16 col-lanes
    int frow4 = (lane >> 4) * 4;
    int fcol = lane & 15;
#pragma unroll
    for (int i = 0; i < 4; ++i) {
#pragma unroll
        for (int q = 0; q < 4; ++q) {
            float s = 0.0f;
#pragma unroll
            for (int j = 0; j < 4; ++j) {
                int col = wc * 64 + j * 16 + fcol;
                float v = acc[i][j][q] + bias1[col];
                v = v > 0.0f ? v : 0.0f;
                s = fmaf(v, wsm[col], s);
            }
            s += __shfl_xor(s, 1);
            s += __shfl_xor(s, 2);
            s += __shfl_xor(s, 4);
            s += __shfl_xor(s, 8);
            if (fcol == 0) red[wr * 64 + i * 16 + frow4 + q][wc] = s;
        }
    }
    __syncthreads();
    if (t < 128) {
        float s = red[t][0] + red[t][1] + red[t][2] + red[t][3] + bias2[0];
        outv[m_base + t] = s > 0.0f ? s : 0.0f;
    }
}

// ---------------- final: softmax over 8 ctx nodes, weighted sum, -L2 distance ----------------
__global__ __launch_bounds__(256) void final_kernel(const float* __restrict__ H,
                                                    const float* __restrict__ UAv,
                                                    const float* __restrict__ UBv,
                                                    float* __restrict__ outv) {
    int b = blockIdx.x;
    int t = threadIdx.x;
    __shared__ float ctx[8][512];
    __shared__ float uas[8], ubs[5];
    __shared__ float red[4];
#pragma unroll
    for (int q = 0; q < 16; ++q) {
        int idx = q * 256 + t;
        int j = idx >> 9, c = idx & 511;
        ctx[j][c] = H[(size_t)(b * 13 + j) * HDIM + c];
    }
    if (t < 8) uas[t] = UAv[b * 8 + t];
    if (t < 5) ubs[t] = UBv[b * 5 + t];
    __syncthreads();
    int c0 = t, c1 = t + 256;
    int wid = t >> 6, lane = t & 63;
    for (int s = 0; s < 5; ++s) {
        float wn[8];
        float sum = 0.0f;
#pragma unroll
        for (int j = 0; j < 8; ++j) {
            wn[j] = __expf(tanhf(uas[j] + ubs[s]));
            sum += wn[j];
        }
        float inv = 1.0f / sum;
        float av0 = 0.0f, av1 = 0.0f;
#pragma unroll
        for (int j = 0; j < 8; ++j) {
            av0 = fmaf(wn[j], ctx[j][c0], av0);
            av1 = fmaf(wn[j], ctx[j][c1], av1);
        }
        av0 *= inv;
        av1 *= inv;
        float d0 = av0 - H[(size_t)(b * 13 + 8 + s) * HDIM + c0];
        float d1 = av1 - H[(size_t)(b * 13 + 8 + s) * HDIM + c1];
        float v = d0 * d0 + d1 * d1;
#pragma unroll
        for (int o = 32; o > 0; o >>= 1) v += __shfl_down(v, o);
        if (lane == 0) red[wid] = v;
        __syncthreads();
        if (t == 0) outv[b * 5 + s] = -sqrtf(red[0] + red[1] + red[2] + red[3]);
        __syncthreads();
    }
}

extern "C" void kernel_launch(void* const* d_in, const int* in_sizes, int n_in,
                              void* d_out, int out_size, void* d_ws, size_t ws_size,
                              hipStream_t stream) {
    const float* Ain  = (const float*)d_in[0];
    const int*   ids  = (const int*)d_in[1];
    const float* emb  = (const float*)d_in[2];
    const float* b_ah = (const float*)d_in[3];
    const float* w_z  = (const float*)d_in[4];
    const float* b_wz = (const float*)d_in[5];
    const float* u_z  = (const float*)d_in[6];
    const float* b_uz = (const float*)d_in[7];
    const float* w_r  = (const float*)d_in[8];
    const float* b_wr = (const float*)d_in[9];
    const float* u_r  = (const float*)d_in[10];
    const float* b_ur = (const float*)d_in[11];
    const float* w_   = (const float*)d_in[12];
    const float* b_w  = (const float*)d_in[13];
    const float* u_u  = (const float*)d_in[14];
    const float* b_u  = (const float*)d_in[15];
    const float* w1   = (const float*)d_in[16];
    const float* b1   = (const float*)d_in[17];
    const float* w12  = (const float*)d_in[18];
    const float* b12  = (const float*)d_in[19];
    const float* w2   = (const float*)d_in[20];
    const float* b2   = (const float*)d_in[21];
    const float* w22  = (const float*)d_in[22];
    const float* b22  = (const float*)d_in[23];
    float* out = (float*)d_out;

    // ---- chunk size: rows=13C divisible by 128 -> C multiple of 128 ----
    // per-elem: Hf4 + Hbf2 + Abf2 + RHbf2 + Zbf2 = 12B
    int C = 128;
    {
        const int cands[6] = {4096, 2048, 1024, 512, 256, 128};
        for (int ci = 0; ci < 6; ++ci) {
            int cc = cands[ci];
            size_t rows = (size_t)13 * cc;
            size_t need = rows * 512 * 12
                        + 6 * (size_t)262144 * 2
                        + 2 * (size_t)131072 * 2
                        + (size_t)13 * cc * 4
                        + (4u << 20);
            if (need <= ws_size) { C = cc; break; }
        }
    }
    const int rows = 13 * C;

    char* base = (char*)d_ws;
    __bf16* Wzb = (__bf16*)base; base += 262144 * 2;
    __bf16* Uzb = (__bf16*)base; base += 262144 * 2;
    __bf16* Wrb = (__bf16*)base; base += 262144 * 2;
    __bf16* Urb = (__bf16*)base; base += 262144 * 2;
    __bf16* Wb  = (__bf16*)base; base += 262144 * 2;
    __bf16* Ub  = (__bf16*)base; base += 262144 * 2;
    __bf16* W1b = (__bf16*)base; base += 131072 * 2;
    __bf16* W2b = (__bf16*)base; base += 131072 * 2;
    float* UA  = (float*)base; base += (size_t)8 * C * 4;
    float* UB  = (float*)base; base += (size_t)5 * C * 4;
    float* Hf  = (float*)base; base += (size_t)rows * 512 * 4;
    __bf16* Hbf  = (__bf16*)base; base += (size_t)rows * 512 * 2;
    __bf16* Abf  = (__bf16*)base; base += (size_t)rows * 512 * 2;
    __bf16* RHbf = (__bf16*)base; base += (size_t)rows * 512 * 2;
    __bf16* Zbf  = (__bf16*)base; base += (size_t)rows * 512 * 2;

    f2bf<<<128, 256, 0, stream>>>(w_z, Wzb, 262144);
    f2bf<<<128, 256, 0, stream>>>(u_z, Uzb, 262144);
    f2bf<<<128, 256, 0, stream>>>(w_r, Wrb, 262144);
    f2bf<<<128, 256, 0, stream>>>(u_r, Urb, 262144);
    f2bf<<<128, 256, 0, stream>>>(w_, Wb, 262144);
    f2bf<<<128, 256, 0, stream>>>(u_u, Ub, 262144);
    f2bf<<<64, 256, 0, stream>>>(w1, W1b, 131072);
    f2bf<<<64, 256, 0, stream>>>(w2, W2b, 131072);

    dim3 ggrid(rows / 128, 4);
    int nblkA = 8 * C / 128;
    int nblkB = 5 * C / 128;
    for (int g0 = 0; g0 < 4096; g0 += C) {
        gather_kernel<<<rows, 512, 0, stream>>>(ids + (size_t)g0 * 52, emb, Hbf);
        for (int it = 0; it < 2; ++it) {
            a_kernel<<<C, 256, 0, stream>>>(Ain + (size_t)g0 * 169, Hbf, b_ah, Abf);
            zr_fused<<<ggrid, 512, 0, stream>>>(Abf, Hbf, Wzb, Uzb, Wrb, Urb,
                                                b_wz, b_uz, b_wr, b_ur, Zbf, RHbf);
            c_fused<<<ggrid, 512, 0, stream>>>(Abf, RHbf, Wb, Ub, b_w, b_u, Zbf, Hf, Hbf,
                                               it == 1 ? 1 : 0);
        }
        score_mfma<<<nblkA + nblkB, 512, 0, stream>>>(Hbf, W1b, W2b, b1, b2, w12, w22,
                                                      b12, b22, UA, UB, nblkA);
        final_kernel<<<C, 256, 0, stream>>>(Hf, UA, UB, out + (size_t)g0 * 5);
    }
}